// Round 12
// baseline (596.807 us; speedup 1.0000x reference)
//
#include <hip/hip_runtime.h>
#include <cstdint>
#include <cstddef>

#define N_NODES 50000
#define M_PAD   50048   // 391 * 128
#define MB_TILES 391    // M_PAD / 128
#define N_EDGES 800000
#define EPB     3125    // edges per bucket-pass block (256 blocks)
#define NBKT    391     // coarse dst buckets (dst >> 7)
#define N_GRAPH 256
#define Z_DIM   2304
#define NREP    16
#define POOL_TOT (N_GRAPH * (128 + 256 + 384))

static constexpr float LEAKY  = 0.01f;
static constexpr float BN_EPS = 1e-5f;

typedef short short8 __attribute__((ext_vector_type(8)));
typedef float floatx4 __attribute__((ext_vector_type(4)));
typedef const __attribute__((address_space(1))) unsigned int* gas_ptr;
typedef __attribute__((address_space(3))) unsigned int* las_ptr;
typedef unsigned long long ull;

__device__ __forceinline__ unsigned short f2b(float f) {
  union { float f; unsigned int u; } v; v.f = f;
  unsigned int u = v.u;
  unsigned int r = (u + 0x7FFFu + ((u >> 16) & 1u)) >> 16;
  return (unsigned short)r;
}
__device__ __forceinline__ float b2f(unsigned short h) {
  union { unsigned int u; float f; } v; v.u = ((unsigned int)h) << 16;
  return v.f;
}
__device__ __forceinline__ unsigned fkey(float x) {
  unsigned k = __float_as_uint(x);
  return k ^ ((k & 0x80000000u) ? 0xFFFFFFFFu : 0x80000000u);
}
__device__ __forceinline__ float kdec(unsigned k) {
  k ^= (k & 0x80000000u) ? 0x80000000u : 0xFFFFFFFFu;
  return __uint_as_float(k);
}

// ---------------- one-shot init ----------------

__global__ void init_all_kernel(int* __restrict__ cntR, int* __restrict__ gcnt,
                                float* __restrict__ sums_all,
                                unsigned* __restrict__ pmaxk, unsigned* __restrict__ pmink,
                                float* __restrict__ psumg) {
  const int i = blockIdx.x * blockDim.x + threadIdx.x;
  if (i < NREP * N_NODES) cntR[i] = 0;
  if (i < N_GRAPH) gcnt[i] = 0;
  if (i < 2 * (128 + 256 + 384)) sums_all[i] = 0.f;
  if (i < POOL_TOT) { pmaxk[i] = 0u; pmink[i] = 0xFFFFFFFFu; psumg[i] = 0.f; }
}

// ---------------- edge pass A: bucket histogram (LDS) + node-degree hist (replicated) ----

__global__ __launch_bounds__(256) void edge_histA_kernel(
    const int* __restrict__ dst, int* __restrict__ bcnt, int* __restrict__ cntR) {
  __shared__ int lh[NBKT];
  const int blk = blockIdx.x;
  const int t = threadIdx.x;
  for (int b = t; b < NBKT; b += 256) lh[b] = 0;
  __syncthreads();
  const int rep = blk & (NREP - 1);
  const int e0 = blk * EPB;
  for (int i = e0 + t; i < e0 + EPB; i += 256) {
    const int d = dst[i];
    atomicAdd(&lh[d >> 7], 1);
    atomicAdd(&cntR[rep * N_NODES + d], 1);
  }
  __syncthreads();
  for (int b = t; b < NBKT; b += 256) bcnt[b * 256 + blk] = lh[b];
}

// ---------------- edge pass C: per-(bucket,block) exclusive offsets, single block ----

__global__ __launch_bounds__(512) void edge_offsets_kernel(int* __restrict__ bcnt,
                                                           int* __restrict__ bbase) {
  __shared__ int sm[512];
  const int t = threadIdx.x;
  int tot = 0;
  if (t < NBKT) {
    const int base = t * 256;
    for (int blk = 0; blk < 256; ++blk) tot += bcnt[base + blk];
  }
  sm[t] = tot;
  __syncthreads();
  for (int off = 1; off < 512; off <<= 1) {
    int x = (t >= off) ? sm[t - off] : 0;
    __syncthreads();
    sm[t] += x;
    __syncthreads();
  }
  const int excl = sm[t] - tot;
  if (t < NBKT) bbase[t] = excl;
  if (t == NBKT - 1) bbase[NBKT] = excl + tot;
  __syncthreads();
  if (t < NBKT) {
    const int base = t * 256;
    int s = excl;
    for (int blk = 0; blk < 256; ++blk) {
      const int c = bcnt[base + blk];
      bcnt[base + blk] = s;
      s += c;
    }
  }
}

// ---------------- edge pass D: scatter into bucket-contiguous order ----------------
// entry: ew<<32 | dlow<<17 | src   (src < 2^17, dlow = dst & 127)

__global__ __launch_bounds__(256) void edge_scatterD_kernel(
    const int* __restrict__ src, const int* __restrict__ dst, const float* __restrict__ ew,
    const int* __restrict__ bcnt, ull* __restrict__ bucketed) {
  __shared__ int loff[NBKT];
  const int blk = blockIdx.x;
  const int t = threadIdx.x;
  for (int b = t; b < NBKT; b += 256) loff[b] = bcnt[b * 256 + blk];
  __syncthreads();
  const int e0 = blk * EPB;
  for (int i = e0 + t; i < e0 + EPB; i += 256) {
    const int d = dst[i];
    const int b = d >> 7;
    const int pos = atomicAdd(&loff[b], 1);
    bucketed[pos] = ((ull)__float_as_uint(ew[i]) << 32) |
                    ((unsigned)(d & 127) << 17) | (unsigned)src[i];
  }
}

// ---------------- edge pass E: bucket -> final CSR order (LDS cursors, L2-local window) ----

__global__ __launch_bounds__(256) void edge_scatterE_kernel(
    const ull* __restrict__ bucketed, const int* __restrict__ bbase,
    const int* __restrict__ rowptr, ull* __restrict__ epack) {
  __shared__ int lcur[128];
  const int b = blockIdx.x;
  const int t = threadIdx.x;
  if (t < 128) {
    const int node = b * 128 + t;
    lcur[t] = (node < N_NODES) ? rowptr[node] : 0;
  }
  __syncthreads();
  const int beg = bbase[b], end = bbase[b + 1];
  for (int i = beg + t; i < end; i += 256) {
    const ull v = bucketed[i];
    const int li = (int)((v >> 17) & 127u);
    const int p = atomicAdd(&lcur[li], 1);
    epack[p] = (v & 0xFFFFFFFF00000000ULL) | (v & 0x1FFFFULL);
  }
}

// ---------------- degree combine + scans ----------------

__global__ void combine_kernel(int* __restrict__ cntR, int* __restrict__ deg, int n) {
  int d = blockIdx.x * blockDim.x + threadIdx.x;
  if (d >= n) return;
  int s = 0;
#pragma unroll
  for (int r = 0; r < NREP; ++r) s += cntR[r * N_NODES + d];
  deg[d] = s;
}

__global__ __launch_bounds__(256) void scan1_kernel(const int* __restrict__ in,
                                                    int* __restrict__ out,
                                                    int* __restrict__ part, int n) {
  __shared__ int sm[256];
  const int t = threadIdx.x;
  const int base = blockIdx.x * 1024 + t * 4;
  int v0 = 0, v1 = 0, v2 = 0, v3 = 0;
  if (base + 3 < n) {
    int4 q = *(const int4*)(in + base);
    v0 = q.x; v1 = q.y; v2 = q.z; v3 = q.w;
  } else {
    if (base     < n) v0 = in[base];
    if (base + 1 < n) v1 = in[base + 1];
    if (base + 2 < n) v2 = in[base + 2];
  }
  const int tsum = v0 + v1 + v2 + v3;
  sm[t] = tsum;
  __syncthreads();
  for (int off = 1; off < 256; off <<= 1) {
    int x = (t >= off) ? sm[t - off] : 0;
    __syncthreads();
    sm[t] += x;
    __syncthreads();
  }
  const int excl = sm[t] - tsum;
  if (base     < n) out[base]     = excl;
  if (base + 1 < n) out[base + 1] = excl + v0;
  if (base + 2 < n) out[base + 2] = excl + v0 + v1;
  if (base + 3 < n) out[base + 3] = excl + v0 + v1 + v2;
  if (t == 255) part[blockIdx.x] = sm[255];
}

__global__ __launch_bounds__(256) void scan2_kernel(int* __restrict__ part, int nb,
                                                    int* __restrict__ total_out) {
  __shared__ int sm[256];
  const int t = threadIdx.x;
  const int v = (t < nb) ? part[t] : 0;
  sm[t] = v;
  __syncthreads();
  for (int off = 1; off < 256; off <<= 1) {
    int x = (t >= off) ? sm[t - off] : 0;
    __syncthreads();
    sm[t] += x;
    __syncthreads();
  }
  if (t < nb) part[t] = sm[t] - v;
  if (t == 255) *total_out = sm[255];
}

__global__ void scan3_kernel(int* __restrict__ out, const int* __restrict__ part, int n) {
  int i = blockIdx.x * blockDim.x + threadIdx.x;
  if (i < n) out[i] += part[i >> 10];
}

__global__ __launch_bounds__(256) void hist_batch_kernel(const int* __restrict__ idx,
                                                         int* __restrict__ cnt, int n) {
  __shared__ int lh[N_GRAPH];
  lh[threadIdx.x] = 0;
  __syncthreads();
  int i = blockIdx.x * blockDim.x + threadIdx.x;
  if (i < n) atomicAdd(&lh[idx[i]], 1);
  __syncthreads();
  const int v = lh[threadIdx.x];
  if (v) atomicAdd(&cnt[threadIdx.x], v);
}

__global__ __launch_bounds__(256) void scan256_kernel(const int* __restrict__ cnt,
                                                      int* __restrict__ gptr) {
  __shared__ int sm[256];
  const int t = threadIdx.x;
  const int v = cnt[t];
  sm[t] = v;
  __syncthreads();
  for (int off = 1; off < 256; off <<= 1) {
    int x = (t >= off) ? sm[t - off] : 0;
    __syncthreads();
    sm[t] += x;
    __syncthreads();
  }
  gptr[t] = sm[t] - v;
  if (t == 255) gptr[256] = sm[255];
}

// ---------------- prep ----------------

__global__ void cast_bf16_kernel(const float* __restrict__ in,
                                 unsigned short* __restrict__ out, int npair) {
  int i = blockIdx.x * blockDim.x + threadIdx.x;
  if (i >= npair) return;
  float2 v = *(const float2*)(in + 2 * (size_t)i);
  ((unsigned int*)out)[i] = (unsigned int)f2b(v.x) | ((unsigned int)f2b(v.y) << 16);
}

__global__ __launch_bounds__(256) void wt_build_kernel(
    const float* __restrict__ wrel, const float* __restrict__ wroot,
    const float* __restrict__ brel, const float* __restrict__ sums_prev,
    const float* __restrict__ gamma_prev, const float* __restrict__ beta_prev,
    unsigned short* __restrict__ wt, float* __restrict__ u, float* __restrict__ v,
    int K, int N) {
  __shared__ float redu[256];
  __shared__ float redv[256];
  const int n = blockIdx.x;
  const int K2 = 2 * K;
  const float inv_n = 1.f / (float)N_NODES;
  float us = 0.f, vs = 0.f;
  for (int k = threadIdx.x; k < K2; k += 256) {
    const int kk = (k < K) ? k : k - K;
    const float w = (k < K) ? wrel[(size_t)kk * N + n] : wroot[(size_t)kk * N + n];
    float sc = 1.f, sh = 0.f;
    if (sums_prev) {
      const float mu  = sums_prev[kk] * inv_n;
      const float var = sums_prev[K + kk] * inv_n - mu * mu;
      sc = rsqrtf(var + BN_EPS) * gamma_prev[kk];
      sh = beta_prev[kk] - mu * sc;
    }
    wt[(size_t)n * K2 + k] = f2b(w * sc);
    if (k < K) us += sh * w; else vs += sh * w;
  }
  redu[threadIdx.x] = us; redv[threadIdx.x] = vs;
  __syncthreads();
  for (int o = 128; o > 0; o >>= 1) {
    if (threadIdx.x < o) {
      redu[threadIdx.x] += redu[threadIdx.x + o];
      redv[threadIdx.x] += redv[threadIdx.x + o];
    }
    __syncthreads();
  }
  if (threadIdx.x == 0) { u[n] = redu[0]; v[n] = brel[n] + redv[0]; }
}

// ---------------- aggregation, 4-edge unrolled; optionally emits degw ----------------

template <int D>
__global__ void agg_bf16_kernel(const unsigned short* __restrict__ h,
                                const int* __restrict__ rowptr,
                                const ull* __restrict__ epack,
                                unsigned short* __restrict__ agg,
                                float* __restrict__ degw_out) {
  int gid  = blockIdx.x * blockDim.x + threadIdx.x;
  int node = gid >> 6;
  int lane = threadIdx.x & 63;
  if (node >= N_NODES) return;
  const int beg = rowptr[node], end = rowptr[node + 1];
  constexpr int NP = D / 128;
  float acc0[NP], acc1[NP];
#pragma unroll
  for (int i = 0; i < NP; ++i) { acc0[i] = 0.f; acc1[i] = 0.f; }
  float wsum = 0.f;

  int p = beg;
  for (; p + 4 <= end; p += 4) {
    const ull p0 = epack[p],     p1 = epack[p + 1];
    const ull p2 = epack[p + 2], p3 = epack[p + 3];
    const int s0 = (int)(unsigned)p0, s1 = (int)(unsigned)p1;
    const int s2 = (int)(unsigned)p2, s3 = (int)(unsigned)p3;
    const float w0 = __uint_as_float((unsigned)(p0 >> 32));
    const float w1 = __uint_as_float((unsigned)(p1 >> 32));
    const float w2 = __uint_as_float((unsigned)(p2 >> 32));
    const float w3 = __uint_as_float((unsigned)(p3 >> 32));
    wsum += w0 + w1 + w2 + w3;
    const unsigned int* r0 = (const unsigned int*)(h + (size_t)s0 * D);
    const unsigned int* r1 = (const unsigned int*)(h + (size_t)s1 * D);
    const unsigned int* r2 = (const unsigned int*)(h + (size_t)s2 * D);
    const unsigned int* r3 = (const unsigned int*)(h + (size_t)s3 * D);
    unsigned int u0[NP], u1[NP], u2[NP], u3[NP];
#pragma unroll
    for (int i = 0; i < NP; ++i) {
      u0[i] = r0[lane + 64 * i];
      u1[i] = r1[lane + 64 * i];
      u2[i] = r2[lane + 64 * i];
      u3[i] = r3[lane + 64 * i];
    }
#pragma unroll
    for (int i = 0; i < NP; ++i) {
      acc0[i] += b2f((unsigned short)(u0[i] & 0xFFFF)) * w0
               + b2f((unsigned short)(u1[i] & 0xFFFF)) * w1
               + b2f((unsigned short)(u2[i] & 0xFFFF)) * w2
               + b2f((unsigned short)(u3[i] & 0xFFFF)) * w3;
      acc1[i] += b2f((unsigned short)(u0[i] >> 16)) * w0
               + b2f((unsigned short)(u1[i] >> 16)) * w1
               + b2f((unsigned short)(u2[i] >> 16)) * w2
               + b2f((unsigned short)(u3[i] >> 16)) * w3;
    }
  }
  for (; p < end; ++p) {
    const ull pk = epack[p];
    const int   s = (int)(unsigned)pk;
    const float w = __uint_as_float((unsigned)(pk >> 32));
    wsum += w;
    const unsigned int* row = (const unsigned int*)(h + (size_t)s * D);
#pragma unroll
    for (int i = 0; i < NP; ++i) {
      unsigned int uu = row[lane + 64 * i];
      acc0[i] += b2f((unsigned short)(uu & 0xFFFF)) * w;
      acc1[i] += b2f((unsigned short)(uu >> 16)) * w;
    }
  }
  unsigned int* o = (unsigned int*)(agg + (size_t)node * D);
#pragma unroll
  for (int i = 0; i < NP; ++i)
    o[lane + 64 * i] = (unsigned int)f2b(acc0[i]) | ((unsigned int)f2b(acc1[i]) << 16);
  if (degw_out != nullptr && lane == 0) degw_out[node] = wsum;
}

// ---------------- MFMA GEMM, global_load_lds staging + XCD-affine tile mapping ----------
// 1D grid of 392*NT blocks: x=id&7, q=id>>3, n_tile=q%NT, m_tile=(q/NT)*8+x
// -> all n-tiles of one m-tile run consecutively on the same XCD (A-tile L2 reuse).

__global__ __launch_bounds__(256) void gemm_mfma_kernel(
    const unsigned short* __restrict__ Aagg, const unsigned short* __restrict__ Ah,
    const unsigned short* __restrict__ Wt,
    const float* __restrict__ u, const float* __restrict__ v,
    const float* __restrict__ degw,
    unsigned short* __restrict__ outH, float* __restrict__ sums,
    int M, int K, int N) {
  __shared__ unsigned short As[128 * 32];
  __shared__ unsigned short Bs[128 * 32];
  __shared__ float col_s[256];
  __shared__ float dws[128];

  const int NT = N >> 7;
  const int id = blockIdx.x;
  const int xcd = id & 7;
  const int q   = id >> 3;
  const int m_tile = (q / NT) * 8 + xcd;
  if (m_tile >= MB_TILES) return;
  const int m0 = m_tile * 128;
  const int n0 = (q % NT) * 128;

  const int t  = threadIdx.x;
  const int lane = t & 63;
  const int w    = t >> 6;
  const int wm   = (w & 1) * 64;
  const int wn   = (w >> 1) * 64;
  const int l16  = lane & 15;
  const int lq   = lane >> 4;
  const int K2   = 2 * K;

  const int lrow  = lane >> 2;
  const int lslot = lane & 3;

  col_s[t] = 0.f;
  if (t < 128) {
    const int m = m0 + t;
    dws[t] = (m < M) ? degw[m] : 0.f;
  }

  floatx4 acc[4][4];
#pragma unroll
  for (int i = 0; i < 4; ++i)
#pragma unroll
    for (int j = 0; j < 4; ++j) acc[i][j] = (floatx4){0.f, 0.f, 0.f, 0.f};

  for (int k0 = 0; k0 < K2; k0 += 32) {
    const unsigned short* Asrc;
    int kbase;
    if (k0 < K) { Asrc = Aagg; kbase = k0; } else { Asrc = Ah; kbase = k0 - K; }

    __syncthreads();
#pragma unroll
    for (int qq = 0; qq < 2; ++qq) {
      const int row = w * 32 + qq * 16 + lrow;
      const int gc  = (lslot ^ ((row >> 1) & 3)) * 8;
      const unsigned short* gA = Asrc + (size_t)(m0 + row) * K + kbase + gc;
      const unsigned short* gB = Wt + (size_t)(n0 + row) * K2 + k0 + gc;
      __builtin_amdgcn_global_load_lds((gas_ptr)gA, (las_ptr)(As + (w * 32 + qq * 16) * 32),
                                       16, 0, 0);
      __builtin_amdgcn_global_load_lds((gas_ptr)gB, (las_ptr)(Bs + (w * 32 + qq * 16) * 32),
                                       16, 0, 0);
    }
    __syncthreads();

    short8 af[4], bfr[4];
#pragma unroll
    for (int i = 0; i < 4; ++i) {
      const int r = wm + i * 16 + l16;
      af[i] = *(const short8*)(As + r * 32 + (lq ^ ((r >> 1) & 3)) * 8);
    }
#pragma unroll
    for (int j = 0; j < 4; ++j) {
      const int r = wn + j * 16 + l16;
      bfr[j] = *(const short8*)(Bs + r * 32 + (lq ^ ((r >> 1) & 3)) * 8);
    }

#pragma unroll
    for (int i = 0; i < 4; ++i)
#pragma unroll
      for (int j = 0; j < 4; ++j)
        acc[i][j] = __builtin_amdgcn_mfma_f32_16x16x32_bf16(af[i], bfr[j], acc[i][j], 0, 0, 0);
  }

  float uu[4], vv[4];
#pragma unroll
  for (int j = 0; j < 4; ++j) {
    const int n = n0 + wn + j * 16 + l16;
    uu[j] = u[n]; vv[j] = v[n];
  }

  float ts[4]  = {0.f, 0.f, 0.f, 0.f};
  float tss[4] = {0.f, 0.f, 0.f, 0.f};
#pragma unroll
  for (int i = 0; i < 4; ++i) {
    const int lrow2 = wm + i * 16 + lq * 4;
#pragma unroll
    for (int j = 0; j < 4; ++j) {
      const int n = n0 + wn + j * 16 + l16;
#pragma unroll
      for (int r = 0; r < 4; ++r) {
        const int m = m0 + lrow2 + r;
        if (m < M) {
          float val = acc[i][j][r] + vv[j] + dws[lrow2 + r] * uu[j];
          val = val > 0.f ? val : LEAKY * val;
          outH[(size_t)m * N + n] = f2b(val);
          ts[j]  += val;
          tss[j] += val * val;
        }
      }
    }
  }
#pragma unroll
  for (int j = 0; j < 4; ++j) {
    float a = ts[j], b = tss[j];
    a += __shfl_xor(a, 16); a += __shfl_xor(a, 32);
    b += __shfl_xor(b, 16); b += __shfl_xor(b, 32);
    if (lq == 0) {
      const int ci = wn + j * 16 + l16;
      atomicAdd(&col_s[ci], a);
      atomicAdd(&col_s[128 + ci], b);
    }
  }
  __syncthreads();
  if (t < 128) {
    atomicAdd(&sums[n0 + t], col_s[t]);
    atomicAdd(&sums[N + n0 + t], col_s[128 + t]);
  }
}

// ---------------- pooling over bf16 hp ----------------

__global__ void pool_bf16_kernel(const unsigned short* __restrict__ hp,
                                 const int* __restrict__ batch,
                                 unsigned* __restrict__ pmaxk, unsigned* __restrict__ pmink,
                                 float* __restrict__ psumg, int n, int C) {
  __shared__ int bs[64];
  const int tc = threadIdx.x;
  const int r0 = blockIdx.x * 64;
  const int r1 = min(n, r0 + 64);
  if (tc < 64 && r0 + tc < n) bs[tc] = batch[r0 + tc];
  __syncthreads();
  int cur_g = bs[0];
  float mx0 = -3.4e38f, mn0 = 3.4e38f, s0 = 0.f;
  float mx1 = -3.4e38f, mn1 = 3.4e38f, s1 = 0.f;
  for (int r = r0; r < r1; ++r) {
    const int g = bs[r - r0];
    if (g != cur_g) {
      const int c0 = 2 * tc;
      atomicMax(&pmaxk[(size_t)cur_g * C + c0], fkey(mx0));
      atomicMin(&pmink[(size_t)cur_g * C + c0], fkey(mn0));
      atomicAdd(&psumg[(size_t)cur_g * C + c0], s0);
      atomicMax(&pmaxk[(size_t)cur_g * C + c0 + 1], fkey(mx1));
      atomicMin(&pmink[(size_t)cur_g * C + c0 + 1], fkey(mn1));
      atomicAdd(&psumg[(size_t)cur_g * C + c0 + 1], s1);
      mx0 = -3.4e38f; mn0 = 3.4e38f; s0 = 0.f;
      mx1 = -3.4e38f; mn1 = 3.4e38f; s1 = 0.f;
      cur_g = g;
    }
    const unsigned uu = ((const unsigned*)(hp + (size_t)r * C))[tc];
    const float a = b2f((unsigned short)(uu & 0xFFFF));
    const float b = b2f((unsigned short)(uu >> 16));
    mx0 = fmaxf(mx0, a); mn0 = fminf(mn0, a); s0 += a;
    mx1 = fmaxf(mx1, b); mn1 = fminf(mn1, b); s1 += b;
  }
  const int c0 = 2 * tc;
  atomicMax(&pmaxk[(size_t)cur_g * C + c0], fkey(mx0));
  atomicMin(&pmink[(size_t)cur_g * C + c0], fkey(mn0));
  atomicAdd(&psumg[(size_t)cur_g * C + c0], s0);
  atomicMax(&pmaxk[(size_t)cur_g * C + c0 + 1], fkey(mx1));
  atomicMin(&pmink[(size_t)cur_g * C + c0 + 1], fkey(mn1));
  atomicAdd(&psumg[(size_t)cur_g * C + c0 + 1], s1);
}

// ---------------- pool finalize ----------------

__global__ void pool_finalize_kernel(const unsigned* __restrict__ pmaxk,
                                     const unsigned* __restrict__ pmink,
                                     const float* __restrict__ psumg,
                                     const float* __restrict__ sums,
                                     const float* __restrict__ gamma,
                                     const float* __restrict__ beta,
                                     const int* __restrict__ gptr,
                                     float* __restrict__ z, int C, int zoff) {
  int i = blockIdx.x * blockDim.x + threadIdx.x;
  if (i >= N_GRAPH * C) return;
  const int g = i / C, c = i % C;
  const int cnt = gptr[g + 1] - gptr[g];
  const float inv_n = 1.f / (float)N_NODES;
  const float mu  = sums[c] * inv_n;
  const float var = sums[C + c] * inv_n - mu * mu;
  const float sc  = rsqrtf(var + BN_EPS) * gamma[c];
  const float sh  = beta[c] - mu * sc;
  const float mx = kdec(pmaxk[i]);
  const float mn = kdec(pmink[i]);
  const float sm = psumg[i];
  const float zmax = (sc >= 0.f ? mx : mn) * sc + sh;
  const float zsum = sm * sc + (float)cnt * sh;
  float* zg = z + (size_t)g * Z_DIM + zoff;
  zg[c]         = (cnt > 0) ? zmax : 0.f;
  zg[C + c]     = zsum / (float)(cnt > 0 ? cnt : 1);
  zg[2 * C + c] = zsum;
}

// ---------------- FC head ----------------

__global__ __launch_bounds__(1024) void fc_kernel(const float* __restrict__ z,
                                                  const float* __restrict__ w1, const float* __restrict__ b1,
                                                  const float* __restrict__ w2, const float* __restrict__ b2,
                                                  const float* __restrict__ w3, const float* __restrict__ b3,
                                                  float* __restrict__ out) {
  __shared__ float zs[Z_DIM];
  __shared__ float part[8][128];
  __shared__ float h1s[128];
  __shared__ float red[128][2];
  __shared__ float y2[2];
  const int g  = blockIdx.x;
  const int t  = threadIdx.x;
  const int c  = t & 127;
  const int ks = t >> 7;
  for (int i = t; i < Z_DIM; i += 1024) zs[i] = z[(size_t)g * Z_DIM + i];
  __syncthreads();

  constexpr int KCH = Z_DIM / 8;
  const int k0 = ks * KCH;
  float acc = 0.f;
#pragma unroll 4
  for (int k = k0; k < k0 + KCH; ++k) acc += zs[k] * w1[(size_t)k * 128 + c];
  part[ks][c] = acc;
  __syncthreads();

  if (t < 128) {
    float s = b1[t];
#pragma unroll
    for (int i = 0; i < 8; ++i) s += part[i][t];
    h1s[t] = fmaxf(s, 0.f);
  }
  __syncthreads();
  if (t < 128) {
    red[t][0] = h1s[t] * w2[t * 2 + 0];
    red[t][1] = h1s[t] * w2[t * 2 + 1];
  }
  __syncthreads();
  if (t < 2) {
    float s = b2[t];
    for (int k = 0; k < 128; ++k) s += red[k][t];
    y2[t] = fmaxf(s, 0.f);
  }
  __syncthreads();
  if (t == 0) {
    const float z0 = y2[0] * w3[0] + y2[1] * w3[2] + b3[0];
    const float z1 = y2[0] * w3[1] + y2[1] * w3[3] + b3[1];
    const float m  = fmaxf(z0, z1);
    const float lse = m + logf(expf(z0 - m) + expf(z1 - m));
    out[g * 2 + 0] = z0 - lse;
    out[g * 2 + 1] = z1 - lse;
  }
}

// ---------------- launch ----------------

extern "C" void kernel_launch(void* const* d_in, const int* in_sizes, int n_in,
                              void* d_out, int out_size, void* d_ws, size_t ws_size,
                              hipStream_t stream) {
  (void)in_sizes; (void)n_in; (void)out_size; (void)ws_size;
  const float* x        = (const float*)d_in[0];
  const int*   eidx     = (const int*)d_in[1];
  const int*   batch    = (const int*)d_in[2];
  const float* eattr    = (const float*)d_in[3];
  const float* w_rel1   = (const float*)d_in[4];
  const float* b_rel1   = (const float*)d_in[5];
  const float* w_root1  = (const float*)d_in[6];
  const float* w_rel2   = (const float*)d_in[7];
  const float* b_rel2   = (const float*)d_in[8];
  const float* w_root2  = (const float*)d_in[9];
  const float* w_rel3   = (const float*)d_in[10];
  const float* b_rel3   = (const float*)d_in[11];
  const float* w_root3  = (const float*)d_in[12];
  const float* gamma1   = (const float*)d_in[13];
  const float* beta1    = (const float*)d_in[14];
  const float* gamma2   = (const float*)d_in[15];
  const float* beta2    = (const float*)d_in[16];
  const float* gamma3   = (const float*)d_in[17];
  const float* beta3    = (const float*)d_in[18];
  const float* w_lin1   = (const float*)d_in[19];
  const float* b_lin1   = (const float*)d_in[20];
  const float* w_lin2   = (const float*)d_in[21];
  const float* b_lin2   = (const float*)d_in[22];
  const float* w_lin3   = (const float*)d_in[23];
  const float* b_lin3   = (const float*)d_in[24];

  const int* src = eidx;
  const int* dst = eidx + N_EDGES;
  float* outp = (float*)d_out;

  char* ws = (char*)d_ws;
  size_t off = 0;
  auto alloc = [&](size_t bytes) -> void* {
    void* p = ws + off;
    off += (bytes + 255) & ~(size_t)255;
    return p;
  };
  int*   rowptr = (int*)alloc((N_NODES + 1) * sizeof(int));
  int*   deg    = (int*)alloc(N_NODES * sizeof(int));
  int*   cntR   = (int*)alloc((size_t)NREP * N_NODES * sizeof(int));
  int*   gptr   = (int*)alloc((N_GRAPH + 1) * sizeof(int));
  int*   gcnt   = (int*)alloc(N_GRAPH * sizeof(int));
  int*   part   = (int*)alloc(256 * sizeof(int));
  int*   bcnt   = (int*)alloc((size_t)NBKT * 256 * sizeof(int));
  int*   bbase  = (int*)alloc((NBKT + 1) * sizeof(int));
  ull*   bucketed = (ull*)alloc((size_t)N_EDGES * sizeof(ull));
  ull*   epack  = (ull*)alloc((size_t)N_EDGES * sizeof(ull));
  float* degw   = (float*)alloc(N_NODES * sizeof(float));
  float* sums_all = (float*)alloc(2 * (128 + 256 + 384) * sizeof(float));
  float* zbuf   = (float*)alloc((size_t)N_GRAPH * Z_DIM * sizeof(float));
  unsigned* pmaxk = (unsigned*)alloc((size_t)POOL_TOT * 4);
  unsigned* pmink = (unsigned*)alloc((size_t)POOL_TOT * 4);
  float*    psumg = (float*)alloc((size_t)POOL_TOT * 4);
  unsigned short* xb   = (unsigned short*)alloc((size_t)M_PAD * 128 * 2);
  unsigned short* hp1  = (unsigned short*)alloc((size_t)M_PAD * 128 * 2);
  unsigned short* hp2  = (unsigned short*)alloc((size_t)M_PAD * 256 * 2);
  unsigned short* hp3  = (unsigned short*)alloc((size_t)M_PAD * 384 * 2);
  unsigned short* aggb = (unsigned short*)alloc((size_t)M_PAD * 256 * 2);
  unsigned short* wt1 = (unsigned short*)alloc((size_t)128 * 256 * 2);
  unsigned short* wt2 = (unsigned short*)alloc((size_t)256 * 256 * 2);
  unsigned short* wt3 = (unsigned short*)alloc((size_t)384 * 512 * 2);
  float* u1 = (float*)alloc(128 * sizeof(float));
  float* v1 = (float*)alloc(128 * sizeof(float));
  float* u2 = (float*)alloc(256 * sizeof(float));
  float* v2 = (float*)alloc(256 * sizeof(float));
  float* u3 = (float*)alloc(384 * sizeof(float));
  float* v3 = (float*)alloc(384 * sizeof(float));

  float* sums1 = sums_all;
  float* sums2 = sums_all + 2 * 128;
  float* sums3 = sums_all + 2 * (128 + 256);
  const int PO1 = 0, PO2 = N_GRAPH * 128, PO3 = N_GRAPH * (128 + 256);

  const int NB = (N_NODES + 255) / 256;
  const int RB = (N_NODES + 63) / 64;
  const int SB = (N_NODES + 1023) / 1024;

  init_all_kernel<<<(NREP * N_NODES + 255) / 256, 256, 0, stream>>>(
      cntR, gcnt, sums_all, pmaxk, pmink, psumg);

  // ---- CSR build: LDS-staged two-pass radix by dst ----
  edge_histA_kernel<<<256, 256, 0, stream>>>(dst, bcnt, cntR);
  combine_kernel<<<NB, 256, 0, stream>>>(cntR, deg, N_NODES);
  scan1_kernel<<<SB, 256, 0, stream>>>(deg, rowptr, part, N_NODES);
  scan2_kernel<<<1, 256, 0, stream>>>(part, SB, rowptr + N_NODES);
  scan3_kernel<<<NB, 256, 0, stream>>>(rowptr, part, N_NODES);
  edge_offsets_kernel<<<1, 512, 0, stream>>>(bcnt, bbase);
  edge_scatterD_kernel<<<256, 256, 0, stream>>>(src, dst, eattr, bcnt, bucketed);
  edge_scatterE_kernel<<<NBKT, 256, 0, stream>>>(bucketed, bbase, rowptr, epack);

  // ---- graph segment pointers ----
  hist_batch_kernel<<<NB, 256, 0, stream>>>(batch, gcnt, N_NODES);
  scan256_kernel<<<1, 256, 0, stream>>>(gcnt, gptr);

  // ---- prep ----
  cast_bf16_kernel<<<(N_NODES * 128 / 2 + 255) / 256, 256, 0, stream>>>(x, xb, N_NODES * 128 / 2);
  wt_build_kernel<<<128, 256, 0, stream>>>(w_rel1, w_root1, b_rel1, nullptr, nullptr, nullptr,
                                           wt1, u1, v1, 128, 128);

  const int aggBlocks = (N_NODES * 64 + 255) / 256;

  // ---- layer 1: 128 -> 128 ----
  agg_bf16_kernel<128><<<aggBlocks, 256, 0, stream>>>(xb, rowptr, epack, aggb, degw);
  gemm_mfma_kernel<<<392 * 1, 256, 0, stream>>>(aggb, xb, wt1, u1, v1, degw,
                                                hp1, sums1, N_NODES, 128, 128);
  pool_bf16_kernel<<<RB, 64, 0, stream>>>(hp1, batch, pmaxk + PO1, pmink + PO1, psumg + PO1,
                                          N_NODES, 128);
  pool_finalize_kernel<<<(N_GRAPH * 128 + 255) / 256, 256, 0, stream>>>(
      pmaxk + PO1, pmink + PO1, psumg + PO1, sums1, gamma1, beta1, gptr, zbuf, 128, 0);
  wt_build_kernel<<<256, 256, 0, stream>>>(w_rel2, w_root2, b_rel2, sums1, gamma1, beta1,
                                           wt2, u2, v2, 128, 256);

  // ---- layer 2: 128 -> 256 ----
  agg_bf16_kernel<128><<<aggBlocks, 256, 0, stream>>>(hp1, rowptr, epack, aggb, nullptr);
  gemm_mfma_kernel<<<392 * 2, 256, 0, stream>>>(aggb, hp1, wt2, u2, v2, degw,
                                                hp2, sums2, N_NODES, 128, 256);
  pool_bf16_kernel<<<RB, 128, 0, stream>>>(hp2, batch, pmaxk + PO2, pmink + PO2, psumg + PO2,
                                           N_NODES, 256);
  pool_finalize_kernel<<<(N_GRAPH * 256 + 255) / 256, 256, 0, stream>>>(
      pmaxk + PO2, pmink + PO2, psumg + PO2, sums2, gamma2, beta2, gptr, zbuf, 256, 384);
  wt_build_kernel<<<384, 256, 0, stream>>>(w_rel3, w_root3, b_rel3, sums2, gamma2, beta2,
                                           wt3, u3, v3, 256, 384);

  // ---- layer 3: 256 -> 384 ----
  agg_bf16_kernel<256><<<aggBlocks, 256, 0, stream>>>(hp2, rowptr, epack, aggb, nullptr);
  gemm_mfma_kernel<<<392 * 3, 256, 0, stream>>>(aggb, hp2, wt3, u3, v3, degw,
                                                hp3, sums3, N_NODES, 256, 384);
  pool_bf16_kernel<<<RB, 192, 0, stream>>>(hp3, batch, pmaxk + PO3, pmink + PO3, psumg + PO3,
                                           N_NODES, 384);
  pool_finalize_kernel<<<(N_GRAPH * 384 + 255) / 256, 256, 0, stream>>>(
      pmaxk + PO3, pmink + PO3, psumg + PO3, sums3, gamma3, beta3, gptr, zbuf, 384, 1152);

  // ---- FC head ----
  fc_kernel<<<N_GRAPH, 1024, 0, stream>>>(zbuf, w_lin1, b_lin1, w_lin2, b_lin2, w_lin3, b_lin3,
                                          outp);
}

// Round 13
// 582.178 us; speedup vs baseline: 1.0251x; 1.0251x over previous
//
#include <hip/hip_runtime.h>
#include <cstdint>
#include <cstddef>

#define N_NODES 50000
#define M_PAD   50048   // 391 * 128
#define MB_TILES 391
#define N_EDGES 800000
#define N_GRAPH 256
#define Z_DIM   2304
#define NREP    16
#define POOL_TOT (N_GRAPH * (128 + 256 + 384))

static constexpr float LEAKY  = 0.01f;
static constexpr float BN_EPS = 1e-5f;

typedef short short8 __attribute__((ext_vector_type(8)));
typedef float floatx4 __attribute__((ext_vector_type(4)));
typedef const __attribute__((address_space(1))) unsigned int* gas_ptr;
typedef __attribute__((address_space(3))) unsigned int* las_ptr;
typedef unsigned long long ull;

__device__ __forceinline__ unsigned short f2b(float f) {
  union { float f; unsigned int u; } v; v.f = f;
  unsigned int u = v.u;
  unsigned int r = (u + 0x7FFFu + ((u >> 16) & 1u)) >> 16;
  return (unsigned short)r;
}
__device__ __forceinline__ float b2f(unsigned short h) {
  union { unsigned int u; float f; } v; v.u = ((unsigned int)h) << 16;
  return v.f;
}
__device__ __forceinline__ unsigned fkey(float x) {
  unsigned k = __float_as_uint(x);
  return k ^ ((k & 0x80000000u) ? 0xFFFFFFFFu : 0x80000000u);
}
__device__ __forceinline__ float kdec(unsigned k) {
  k ^= (k & 0x80000000u) ? 0x80000000u : 0xFFFFFFFFu;
  return __uint_as_float(k);
}

// ---------------- one-shot init ----------------

__global__ void init_all_kernel(int* __restrict__ cntR, int* __restrict__ gcnt,
                                float* __restrict__ sums_all,
                                unsigned* __restrict__ pmaxk, unsigned* __restrict__ pmink,
                                float* __restrict__ psumg) {
  const int i = blockIdx.x * blockDim.x + threadIdx.x;
  if (i < NREP * N_NODES) cntR[i] = 0;
  if (i < N_GRAPH) gcnt[i] = 0;
  if (i < 2 * (128 + 256 + 384)) sums_all[i] = 0.f;
  if (i < POOL_TOT) { pmaxk[i] = 0u; pmink[i] = 0xFFFFFFFFu; psumg[i] = 0.f; }
}

// ---------------- CSR build (replicated histogram/cursor, round-11 scheme) ----------------

__global__ void hist_rep_kernel(const int* __restrict__ idx, int* __restrict__ cntR, int n) {
  int i = blockIdx.x * blockDim.x + threadIdx.x;
  if (i < n) {
    const int rep = blockIdx.x & (NREP - 1);
    atomicAdd(&cntR[rep * N_NODES + idx[i]], 1);
  }
}

__global__ void combine_kernel(int* __restrict__ cntR, int* __restrict__ deg, int n) {
  int d = blockIdx.x * blockDim.x + threadIdx.x;
  if (d >= n) return;
  int s = 0;
#pragma unroll
  for (int r = 0; r < NREP; ++r) {
    const int c = cntR[r * N_NODES + d];
    cntR[r * N_NODES + d] = s;
    s += c;
  }
  deg[d] = s;
}

__global__ __launch_bounds__(256) void scan1_kernel(const int* __restrict__ in,
                                                    int* __restrict__ out,
                                                    int* __restrict__ part, int n) {
  __shared__ int sm[256];
  const int t = threadIdx.x;
  const int base = blockIdx.x * 1024 + t * 4;
  int v0 = 0, v1 = 0, v2 = 0, v3 = 0;
  if (base + 3 < n) {
    int4 q = *(const int4*)(in + base);
    v0 = q.x; v1 = q.y; v2 = q.z; v3 = q.w;
  } else {
    if (base     < n) v0 = in[base];
    if (base + 1 < n) v1 = in[base + 1];
    if (base + 2 < n) v2 = in[base + 2];
  }
  const int tsum = v0 + v1 + v2 + v3;
  sm[t] = tsum;
  __syncthreads();
  for (int off = 1; off < 256; off <<= 1) {
    int x = (t >= off) ? sm[t - off] : 0;
    __syncthreads();
    sm[t] += x;
    __syncthreads();
  }
  const int excl = sm[t] - tsum;
  if (base     < n) out[base]     = excl;
  if (base + 1 < n) out[base + 1] = excl + v0;
  if (base + 2 < n) out[base + 2] = excl + v0 + v1;
  if (base + 3 < n) out[base + 3] = excl + v0 + v1 + v2;
  if (t == 255) part[blockIdx.x] = sm[255];
}

__global__ __launch_bounds__(256) void scan2_kernel(int* __restrict__ part, int nb,
                                                    int* __restrict__ total_out) {
  __shared__ int sm[256];
  const int t = threadIdx.x;
  const int v = (t < nb) ? part[t] : 0;
  sm[t] = v;
  __syncthreads();
  for (int off = 1; off < 256; off <<= 1) {
    int x = (t >= off) ? sm[t - off] : 0;
    __syncthreads();
    sm[t] += x;
    __syncthreads();
  }
  if (t < nb) part[t] = sm[t] - v;
  if (t == 255) *total_out = sm[255];
}

__global__ void scan3_cursor_kernel(int* __restrict__ out, const int* __restrict__ part,
                                    int* __restrict__ cntR, int n) {
  int i = blockIdx.x * blockDim.x + threadIdx.x;
  if (i >= n) return;
  const int rp = out[i] + part[i >> 10];
  out[i] = rp;
#pragma unroll
  for (int r = 0; r < NREP; ++r) cntR[r * N_NODES + i] += rp;
}

__global__ void bucket_kernel(const int* __restrict__ src, const int* __restrict__ dst,
                              const float* __restrict__ ew, int* __restrict__ cntR,
                              ull* __restrict__ epack, int E) {
  int e = blockIdx.x * blockDim.x + threadIdx.x;
  if (e < E) {
    const int rep = blockIdx.x & (NREP - 1);
    const int d = dst[e];
    const int p = atomicAdd(&cntR[rep * N_NODES + d], 1);
    epack[p] = ((ull)__float_as_uint(ew[e]) << 32) | (unsigned)src[e];
  }
}

__global__ __launch_bounds__(256) void hist_batch_kernel(const int* __restrict__ idx,
                                                         int* __restrict__ cnt, int n) {
  __shared__ int lh[N_GRAPH];
  lh[threadIdx.x] = 0;
  __syncthreads();
  int i = blockIdx.x * blockDim.x + threadIdx.x;
  if (i < n) atomicAdd(&lh[idx[i]], 1);
  __syncthreads();
  const int v = lh[threadIdx.x];
  if (v) atomicAdd(&cnt[threadIdx.x], v);
}

__global__ __launch_bounds__(256) void scan256_kernel(const int* __restrict__ cnt,
                                                      int* __restrict__ gptr) {
  __shared__ int sm[256];
  const int t = threadIdx.x;
  const int v = cnt[t];
  sm[t] = v;
  __syncthreads();
  for (int off = 1; off < 256; off <<= 1) {
    int x = (t >= off) ? sm[t - off] : 0;
    __syncthreads();
    sm[t] += x;
    __syncthreads();
  }
  gptr[t] = sm[t] - v;
  if (t == 255) gptr[256] = sm[255];
}

// ---------------- prep ----------------

__global__ void cast_bf16_kernel(const float* __restrict__ in,
                                 unsigned short* __restrict__ out, int npair) {
  int i = blockIdx.x * blockDim.x + threadIdx.x;
  if (i >= npair) return;
  float2 v = *(const float2*)(in + 2 * (size_t)i);
  ((unsigned int*)out)[i] = (unsigned int)f2b(v.x) | ((unsigned int)f2b(v.y) << 16);
}

__global__ __launch_bounds__(256) void wt_build_kernel(
    const float* __restrict__ wrel, const float* __restrict__ wroot,
    const float* __restrict__ brel, const float* __restrict__ sums_prev,
    const float* __restrict__ gamma_prev, const float* __restrict__ beta_prev,
    unsigned short* __restrict__ wt, float* __restrict__ u, float* __restrict__ v,
    int K, int N) {
  __shared__ float redu[256];
  __shared__ float redv[256];
  const int n = blockIdx.x;
  const int K2 = 2 * K;
  const float inv_n = 1.f / (float)N_NODES;
  float us = 0.f, vs = 0.f;
  for (int k = threadIdx.x; k < K2; k += 256) {
    const int kk = (k < K) ? k : k - K;
    const float w = (k < K) ? wrel[(size_t)kk * N + n] : wroot[(size_t)kk * N + n];
    float sc = 1.f, sh = 0.f;
    if (sums_prev) {
      const float mu  = sums_prev[kk] * inv_n;
      const float var = sums_prev[K + kk] * inv_n - mu * mu;
      sc = rsqrtf(var + BN_EPS) * gamma_prev[kk];
      sh = beta_prev[kk] - mu * sc;
    }
    wt[(size_t)n * K2 + k] = f2b(w * sc);
    if (k < K) us += sh * w; else vs += sh * w;
  }
  redu[threadIdx.x] = us; redv[threadIdx.x] = vs;
  __syncthreads();
  for (int o = 128; o > 0; o >>= 1) {
    if (threadIdx.x < o) {
      redu[threadIdx.x] += redu[threadIdx.x + o];
      redv[threadIdx.x] += redv[threadIdx.x + o];
    }
    __syncthreads();
  }
  if (threadIdx.x == 0) { u[n] = redu[0]; v[n] = brel[n] + redv[0]; }
}

// ---------------- aggregation, 4-edge unrolled; optionally emits degw ----------------

template <int D>
__global__ void agg_bf16_kernel(const unsigned short* __restrict__ h,
                                const int* __restrict__ rowptr,
                                const ull* __restrict__ epack,
                                unsigned short* __restrict__ agg,
                                float* __restrict__ degw_out) {
  int gid  = blockIdx.x * blockDim.x + threadIdx.x;
  int node = gid >> 6;
  int lane = threadIdx.x & 63;
  if (node >= N_NODES) return;
  const int beg = rowptr[node], end = rowptr[node + 1];
  constexpr int NP = D / 128;
  float acc0[NP], acc1[NP];
#pragma unroll
  for (int i = 0; i < NP; ++i) { acc0[i] = 0.f; acc1[i] = 0.f; }
  float wsum = 0.f;

  int p = beg;
  for (; p + 4 <= end; p += 4) {
    const ull p0 = epack[p],     p1 = epack[p + 1];
    const ull p2 = epack[p + 2], p3 = epack[p + 3];
    const int s0 = (int)(unsigned)p0, s1 = (int)(unsigned)p1;
    const int s2 = (int)(unsigned)p2, s3 = (int)(unsigned)p3;
    const float w0 = __uint_as_float((unsigned)(p0 >> 32));
    const float w1 = __uint_as_float((unsigned)(p1 >> 32));
    const float w2 = __uint_as_float((unsigned)(p2 >> 32));
    const float w3 = __uint_as_float((unsigned)(p3 >> 32));
    wsum += w0 + w1 + w2 + w3;
    const unsigned int* r0 = (const unsigned int*)(h + (size_t)s0 * D);
    const unsigned int* r1 = (const unsigned int*)(h + (size_t)s1 * D);
    const unsigned int* r2 = (const unsigned int*)(h + (size_t)s2 * D);
    const unsigned int* r3 = (const unsigned int*)(h + (size_t)s3 * D);
    unsigned int u0[NP], u1[NP], u2[NP], u3[NP];
#pragma unroll
    for (int i = 0; i < NP; ++i) {
      u0[i] = r0[lane + 64 * i];
      u1[i] = r1[lane + 64 * i];
      u2[i] = r2[lane + 64 * i];
      u3[i] = r3[lane + 64 * i];
    }
#pragma unroll
    for (int i = 0; i < NP; ++i) {
      acc0[i] += b2f((unsigned short)(u0[i] & 0xFFFF)) * w0
               + b2f((unsigned short)(u1[i] & 0xFFFF)) * w1
               + b2f((unsigned short)(u2[i] & 0xFFFF)) * w2
               + b2f((unsigned short)(u3[i] & 0xFFFF)) * w3;
      acc1[i] += b2f((unsigned short)(u0[i] >> 16)) * w0
               + b2f((unsigned short)(u1[i] >> 16)) * w1
               + b2f((unsigned short)(u2[i] >> 16)) * w2
               + b2f((unsigned short)(u3[i] >> 16)) * w3;
    }
  }
  for (; p < end; ++p) {
    const ull pk = epack[p];
    const int   s = (int)(unsigned)pk;
    const float w = __uint_as_float((unsigned)(pk >> 32));
    wsum += w;
    const unsigned int* row = (const unsigned int*)(h + (size_t)s * D);
#pragma unroll
    for (int i = 0; i < NP; ++i) {
      unsigned int uu = row[lane + 64 * i];
      acc0[i] += b2f((unsigned short)(uu & 0xFFFF)) * w;
      acc1[i] += b2f((unsigned short)(uu >> 16)) * w;
    }
  }
  unsigned int* o = (unsigned int*)(agg + (size_t)node * D);
#pragma unroll
  for (int i = 0; i < NP; ++i)
    o[lane + 64 * i] = (unsigned int)f2b(acc0[i]) | ((unsigned int)f2b(acc1[i]) << 16);
  if (degw_out != nullptr && lane == 0) degw_out[node] = wsum;
}

// ---------------- MFMA GEMM: global_load_lds + XCD-affine tiles + BK=64 window ----------
// Two 32-wide K-subtiles staged per barrier window (halves barrier drains, 2x MLP).

__global__ __launch_bounds__(256) void gemm_mfma_kernel(
    const unsigned short* __restrict__ Aagg, const unsigned short* __restrict__ Ah,
    const unsigned short* __restrict__ Wt,
    const float* __restrict__ u, const float* __restrict__ v,
    const float* __restrict__ degw,
    unsigned short* __restrict__ outH, float* __restrict__ sums,
    int M, int K, int N) {
  __shared__ unsigned short As[2][128 * 32];
  __shared__ unsigned short Bs[2][128 * 32];
  __shared__ float col_s[256];
  __shared__ float dws[128];

  const int NT = N >> 7;
  const int id = blockIdx.x;
  const int xcd = id & 7;
  const int q   = id >> 3;
  const int m_tile = (q / NT) * 8 + xcd;
  if (m_tile >= MB_TILES) return;
  const int m0 = m_tile * 128;
  const int n0 = (q % NT) * 128;

  const int t  = threadIdx.x;
  const int lane = t & 63;
  const int w    = t >> 6;
  const int wm   = (w & 1) * 64;
  const int wn   = (w >> 1) * 64;
  const int l16  = lane & 15;
  const int lq   = lane >> 4;
  const int K2   = 2 * K;

  const int lrow  = lane >> 2;
  const int lslot = lane & 3;

  col_s[t] = 0.f;
  if (t < 128) {
    const int m = m0 + t;
    dws[t] = (m < M) ? degw[m] : 0.f;
  }

  floatx4 acc[4][4];
#pragma unroll
  for (int i = 0; i < 4; ++i)
#pragma unroll
    for (int j = 0; j < 4; ++j) acc[i][j] = (floatx4){0.f, 0.f, 0.f, 0.f};

  for (int k0 = 0; k0 < K2; k0 += 64) {
    __syncthreads();  // WAR: previous window's ds_reads done
#pragma unroll
    for (int h = 0; h < 2; ++h) {
      const int kk = k0 + h * 32;
      const unsigned short* Asrc;
      int kbase;
      if (kk < K) { Asrc = Aagg; kbase = kk; } else { Asrc = Ah; kbase = kk - K; }
#pragma unroll
      for (int qq = 0; qq < 2; ++qq) {
        const int row = w * 32 + qq * 16 + lrow;
        const int gc  = (lslot ^ ((row >> 1) & 3)) * 8;
        const unsigned short* gA = Asrc + (size_t)(m0 + row) * K + kbase + gc;
        const unsigned short* gB = Wt + (size_t)(n0 + row) * K2 + kk + gc;
        __builtin_amdgcn_global_load_lds((gas_ptr)gA,
                                         (las_ptr)(As[h] + (w * 32 + qq * 16) * 32), 16, 0, 0);
        __builtin_amdgcn_global_load_lds((gas_ptr)gB,
                                         (las_ptr)(Bs[h] + (w * 32 + qq * 16) * 32), 16, 0, 0);
      }
    }
    __syncthreads();  // drain: both subtiles in LDS

#pragma unroll
    for (int h = 0; h < 2; ++h) {
      short8 af[4], bfr[4];
#pragma unroll
      for (int i = 0; i < 4; ++i) {
        const int r = wm + i * 16 + l16;
        af[i] = *(const short8*)(As[h] + r * 32 + (lq ^ ((r >> 1) & 3)) * 8);
      }
#pragma unroll
      for (int j = 0; j < 4; ++j) {
        const int r = wn + j * 16 + l16;
        bfr[j] = *(const short8*)(Bs[h] + r * 32 + (lq ^ ((r >> 1) & 3)) * 8);
      }
#pragma unroll
      for (int i = 0; i < 4; ++i)
#pragma unroll
        for (int j = 0; j < 4; ++j)
          acc[i][j] = __builtin_amdgcn_mfma_f32_16x16x32_bf16(af[i], bfr[j], acc[i][j], 0, 0, 0);
    }
  }

  float uu[4], vv[4];
#pragma unroll
  for (int j = 0; j < 4; ++j) {
    const int n = n0 + wn + j * 16 + l16;
    uu[j] = u[n]; vv[j] = v[n];
  }

  float ts[4]  = {0.f, 0.f, 0.f, 0.f};
  float tss[4] = {0.f, 0.f, 0.f, 0.f};
#pragma unroll
  for (int i = 0; i < 4; ++i) {
    const int lrow2 = wm + i * 16 + lq * 4;
#pragma unroll
    for (int j = 0; j < 4; ++j) {
      const int n = n0 + wn + j * 16 + l16;
#pragma unroll
      for (int r = 0; r < 4; ++r) {
        const int m = m0 + lrow2 + r;
        if (m < M) {
          float val = acc[i][j][r] + vv[j] + dws[lrow2 + r] * uu[j];
          val = val > 0.f ? val : LEAKY * val;
          outH[(size_t)m * N + n] = f2b(val);
          ts[j]  += val;
          tss[j] += val * val;
        }
      }
    }
  }
#pragma unroll
  for (int j = 0; j < 4; ++j) {
    float a = ts[j], b = tss[j];
    a += __shfl_xor(a, 16); a += __shfl_xor(a, 32);
    b += __shfl_xor(b, 16); b += __shfl_xor(b, 32);
    if (lq == 0) {
      const int ci = wn + j * 16 + l16;
      atomicAdd(&col_s[ci], a);
      atomicAdd(&col_s[128 + ci], b);
    }
  }
  __syncthreads();
  if (t < 128) {
    atomicAdd(&sums[n0 + t], col_s[t]);
    atomicAdd(&sums[N + n0 + t], col_s[128 + t]);
  }
}

// ---------------- pooling over bf16 hp ----------------

__global__ void pool_bf16_kernel(const unsigned short* __restrict__ hp,
                                 const int* __restrict__ batch,
                                 unsigned* __restrict__ pmaxk, unsigned* __restrict__ pmink,
                                 float* __restrict__ psumg, int n, int C) {
  __shared__ int bs[64];
  const int tc = threadIdx.x;
  const int r0 = blockIdx.x * 64;
  const int r1 = min(n, r0 + 64);
  if (tc < 64 && r0 + tc < n) bs[tc] = batch[r0 + tc];
  __syncthreads();
  int cur_g = bs[0];
  float mx0 = -3.4e38f, mn0 = 3.4e38f, s0 = 0.f;
  float mx1 = -3.4e38f, mn1 = 3.4e38f, s1 = 0.f;
  for (int r = r0; r < r1; ++r) {
    const int g = bs[r - r0];
    if (g != cur_g) {
      const int c0 = 2 * tc;
      atomicMax(&pmaxk[(size_t)cur_g * C + c0], fkey(mx0));
      atomicMin(&pmink[(size_t)cur_g * C + c0], fkey(mn0));
      atomicAdd(&psumg[(size_t)cur_g * C + c0], s0);
      atomicMax(&pmaxk[(size_t)cur_g * C + c0 + 1], fkey(mx1));
      atomicMin(&pmink[(size_t)cur_g * C + c0 + 1], fkey(mn1));
      atomicAdd(&psumg[(size_t)cur_g * C + c0 + 1], s1);
      mx0 = -3.4e38f; mn0 = 3.4e38f; s0 = 0.f;
      mx1 = -3.4e38f; mn1 = 3.4e38f; s1 = 0.f;
      cur_g = g;
    }
    const unsigned uu = ((const unsigned*)(hp + (size_t)r * C))[tc];
    const float a = b2f((unsigned short)(uu & 0xFFFF));
    const float b = b2f((unsigned short)(uu >> 16));
    mx0 = fmaxf(mx0, a); mn0 = fminf(mn0, a); s0 += a;
    mx1 = fmaxf(mx1, b); mn1 = fminf(mn1, b); s1 += b;
  }
  const int c0 = 2 * tc;
  atomicMax(&pmaxk[(size_t)cur_g * C + c0], fkey(mx0));
  atomicMin(&pmink[(size_t)cur_g * C + c0], fkey(mn0));
  atomicAdd(&psumg[(size_t)cur_g * C + c0], s0);
  atomicMax(&pmaxk[(size_t)cur_g * C + c0 + 1], fkey(mx1));
  atomicMin(&pmink[(size_t)cur_g * C + c0 + 1], fkey(mn1));
  atomicAdd(&psumg[(size_t)cur_g * C + c0 + 1], s1);
}

// ---------------- pool finalize ----------------

__global__ void pool_finalize_kernel(const unsigned* __restrict__ pmaxk,
                                     const unsigned* __restrict__ pmink,
                                     const float* __restrict__ psumg,
                                     const float* __restrict__ sums,
                                     const float* __restrict__ gamma,
                                     const float* __restrict__ beta,
                                     const int* __restrict__ gptr,
                                     float* __restrict__ z, int C, int zoff) {
  int i = blockIdx.x * blockDim.x + threadIdx.x;
  if (i >= N_GRAPH * C) return;
  const int g = i / C, c = i % C;
  const int cnt = gptr[g + 1] - gptr[g];
  const float inv_n = 1.f / (float)N_NODES;
  const float mu  = sums[c] * inv_n;
  const float var = sums[C + c] * inv_n - mu * mu;
  const float sc  = rsqrtf(var + BN_EPS) * gamma[c];
  const float sh  = beta[c] - mu * sc;
  const float mx = kdec(pmaxk[i]);
  const float mn = kdec(pmink[i]);
  const float sm = psumg[i];
  const float zmax = (sc >= 0.f ? mx : mn) * sc + sh;
  const float zsum = sm * sc + (float)cnt * sh;
  float* zg = z + (size_t)g * Z_DIM + zoff;
  zg[c]         = (cnt > 0) ? zmax : 0.f;
  zg[C + c]     = zsum / (float)(cnt > 0 ? cnt : 1);
  zg[2 * C + c] = zsum;
}

// ---------------- FC head ----------------

__global__ __launch_bounds__(1024) void fc_kernel(const float* __restrict__ z,
                                                  const float* __restrict__ w1, const float* __restrict__ b1,
                                                  const float* __restrict__ w2, const float* __restrict__ b2,
                                                  const float* __restrict__ w3, const float* __restrict__ b3,
                                                  float* __restrict__ out) {
  __shared__ float zs[Z_DIM];
  __shared__ float part[8][128];
  __shared__ float h1s[128];
  __shared__ float red[128][2];
  __shared__ float y2[2];
  const int g  = blockIdx.x;
  const int t  = threadIdx.x;
  const int c  = t & 127;
  const int ks = t >> 7;
  for (int i = t; i < Z_DIM; i += 1024) zs[i] = z[(size_t)g * Z_DIM + i];
  __syncthreads();

  constexpr int KCH = Z_DIM / 8;
  const int k0 = ks * KCH;
  float acc = 0.f;
#pragma unroll 4
  for (int k = k0; k < k0 + KCH; ++k) acc += zs[k] * w1[(size_t)k * 128 + c];
  part[ks][c] = acc;
  __syncthreads();

  if (t < 128) {
    float s = b1[t];
#pragma unroll
    for (int i = 0; i < 8; ++i) s += part[i][t];
    h1s[t] = fmaxf(s, 0.f);
  }
  __syncthreads();
  if (t < 128) {
    red[t][0] = h1s[t] * w2[t * 2 + 0];
    red[t][1] = h1s[t] * w2[t * 2 + 1];
  }
  __syncthreads();
  if (t < 2) {
    float s = b2[t];
    for (int k = 0; k < 128; ++k) s += red[k][t];
    y2[t] = fmaxf(s, 0.f);
  }
  __syncthreads();
  if (t == 0) {
    const float z0 = y2[0] * w3[0] + y2[1] * w3[2] + b3[0];
    const float z1 = y2[0] * w3[1] + y2[1] * w3[3] + b3[1];
    const float m  = fmaxf(z0, z1);
    const float lse = m + logf(expf(z0 - m) + expf(z1 - m));
    out[g * 2 + 0] = z0 - lse;
    out[g * 2 + 1] = z1 - lse;
  }
}

// ---------------- launch ----------------

extern "C" void kernel_launch(void* const* d_in, const int* in_sizes, int n_in,
                              void* d_out, int out_size, void* d_ws, size_t ws_size,
                              hipStream_t stream) {
  (void)in_sizes; (void)n_in; (void)out_size; (void)ws_size;
  const float* x        = (const float*)d_in[0];
  const int*   eidx     = (const int*)d_in[1];
  const int*   batch    = (const int*)d_in[2];
  const float* eattr    = (const float*)d_in[3];
  const float* w_rel1   = (const float*)d_in[4];
  const float* b_rel1   = (const float*)d_in[5];
  const float* w_root1  = (const float*)d_in[6];
  const float* w_rel2   = (const float*)d_in[7];
  const float* b_rel2   = (const float*)d_in[8];
  const float* w_root2  = (const float*)d_in[9];
  const float* w_rel3   = (const float*)d_in[10];
  const float* b_rel3   = (const float*)d_in[11];
  const float* w_root3  = (const float*)d_in[12];
  const float* gamma1   = (const float*)d_in[13];
  const float* beta1    = (const float*)d_in[14];
  const float* gamma2   = (const float*)d_in[15];
  const float* beta2    = (const float*)d_in[16];
  const float* gamma3   = (const float*)d_in[17];
  const float* beta3    = (const float*)d_in[18];
  const float* w_lin1   = (const float*)d_in[19];
  const float* b_lin1   = (const float*)d_in[20];
  const float* w_lin2   = (const float*)d_in[21];
  const float* b_lin2   = (const float*)d_in[22];
  const float* w_lin3   = (const float*)d_in[23];
  const float* b_lin3   = (const float*)d_in[24];

  const int* src = eidx;
  const int* dst = eidx + N_EDGES;
  float* outp = (float*)d_out;

  char* ws = (char*)d_ws;
  size_t off = 0;
  auto alloc = [&](size_t bytes) -> void* {
    void* p = ws + off;
    off += (bytes + 255) & ~(size_t)255;
    return p;
  };
  int*   rowptr = (int*)alloc((N_NODES + 1) * sizeof(int));
  int*   deg    = (int*)alloc(N_NODES * sizeof(int));
  int*   cntR   = (int*)alloc((size_t)NREP * N_NODES * sizeof(int));
  int*   gptr   = (int*)alloc((N_GRAPH + 1) * sizeof(int));
  int*   gcnt   = (int*)alloc(N_GRAPH * sizeof(int));
  int*   part   = (int*)alloc(256 * sizeof(int));
  ull*   epack  = (ull*)alloc((size_t)N_EDGES * sizeof(ull));
  float* degw   = (float*)alloc(N_NODES * sizeof(float));
  float* sums_all = (float*)alloc(2 * (128 + 256 + 384) * sizeof(float));
  float* zbuf   = (float*)alloc((size_t)N_GRAPH * Z_DIM * sizeof(float));
  unsigned* pmaxk = (unsigned*)alloc((size_t)POOL_TOT * 4);
  unsigned* pmink = (unsigned*)alloc((size_t)POOL_TOT * 4);
  float*    psumg = (float*)alloc((size_t)POOL_TOT * 4);
  unsigned short* xb   = (unsigned short*)alloc((size_t)M_PAD * 128 * 2);
  unsigned short* hp1  = (unsigned short*)alloc((size_t)M_PAD * 128 * 2);
  unsigned short* hp2  = (unsigned short*)alloc((size_t)M_PAD * 256 * 2);
  unsigned short* hp3  = (unsigned short*)alloc((size_t)M_PAD * 384 * 2);
  unsigned short* aggb = (unsigned short*)alloc((size_t)M_PAD * 256 * 2);
  unsigned short* wt1 = (unsigned short*)alloc((size_t)128 * 256 * 2);
  unsigned short* wt2 = (unsigned short*)alloc((size_t)256 * 256 * 2);
  unsigned short* wt3 = (unsigned short*)alloc((size_t)384 * 512 * 2);
  float* u1 = (float*)alloc(128 * sizeof(float));
  float* v1 = (float*)alloc(128 * sizeof(float));
  float* u2 = (float*)alloc(256 * sizeof(float));
  float* v2 = (float*)alloc(256 * sizeof(float));
  float* u3 = (float*)alloc(384 * sizeof(float));
  float* v3 = (float*)alloc(384 * sizeof(float));

  float* sums1 = sums_all;
  float* sums2 = sums_all + 2 * 128;
  float* sums3 = sums_all + 2 * (128 + 256);
  const int PO1 = 0, PO2 = N_GRAPH * 128, PO3 = N_GRAPH * (128 + 256);

  const int EB = (N_EDGES + 255) / 256;
  const int NB = (N_NODES + 255) / 256;
  const int RB = (N_NODES + 63) / 64;
  const int SB = (N_NODES + 1023) / 1024;

  init_all_kernel<<<(NREP * N_NODES + 255) / 256, 256, 0, stream>>>(
      cntR, gcnt, sums_all, pmaxk, pmink, psumg);

  // ---- CSR by dst (round-11 replicated-cursor scheme) ----
  hist_rep_kernel<<<EB, 256, 0, stream>>>(dst, cntR, N_EDGES);
  combine_kernel<<<NB, 256, 0, stream>>>(cntR, deg, N_NODES);
  scan1_kernel<<<SB, 256, 0, stream>>>(deg, rowptr, part, N_NODES);
  scan2_kernel<<<1, 256, 0, stream>>>(part, SB, rowptr + N_NODES);
  scan3_cursor_kernel<<<NB, 256, 0, stream>>>(rowptr, part, cntR, N_NODES);
  bucket_kernel<<<EB, 256, 0, stream>>>(src, dst, eattr, cntR, epack, N_EDGES);

  // ---- graph segment pointers ----
  hist_batch_kernel<<<NB, 256, 0, stream>>>(batch, gcnt, N_NODES);
  scan256_kernel<<<1, 256, 0, stream>>>(gcnt, gptr);

  // ---- prep ----
  cast_bf16_kernel<<<(N_NODES * 128 / 2 + 255) / 256, 256, 0, stream>>>(x, xb, N_NODES * 128 / 2);
  wt_build_kernel<<<128, 256, 0, stream>>>(w_rel1, w_root1, b_rel1, nullptr, nullptr, nullptr,
                                           wt1, u1, v1, 128, 128);

  const int aggBlocks = (N_NODES * 64 + 255) / 256;

  // ---- layer 1: 128 -> 128 ----
  agg_bf16_kernel<128><<<aggBlocks, 256, 0, stream>>>(xb, rowptr, epack, aggb, degw);
  gemm_mfma_kernel<<<392 * 1, 256, 0, stream>>>(aggb, xb, wt1, u1, v1, degw,
                                                hp1, sums1, N_NODES, 128, 128);
  pool_bf16_kernel<<<RB, 64, 0, stream>>>(hp1, batch, pmaxk + PO1, pmink + PO1, psumg + PO1,
                                          N_NODES, 128);
  pool_finalize_kernel<<<(N_GRAPH * 128 + 255) / 256, 256, 0, stream>>>(
      pmaxk + PO1, pmink + PO1, psumg + PO1, sums1, gamma1, beta1, gptr, zbuf, 128, 0);
  wt_build_kernel<<<256, 256, 0, stream>>>(w_rel2, w_root2, b_rel2, sums1, gamma1, beta1,
                                           wt2, u2, v2, 128, 256);

  // ---- layer 2: 128 -> 256 ----
  agg_bf16_kernel<128><<<aggBlocks, 256, 0, stream>>>(hp1, rowptr, epack, aggb, nullptr);
  gemm_mfma_kernel<<<392 * 2, 256, 0, stream>>>(aggb, hp1, wt2, u2, v2, degw,
                                                hp2, sums2, N_NODES, 128, 256);
  pool_bf16_kernel<<<RB, 128, 0, stream>>>(hp2, batch, pmaxk + PO2, pmink + PO2, psumg + PO2,
                                           N_NODES, 256);
  pool_finalize_kernel<<<(N_GRAPH * 256 + 255) / 256, 256, 0, stream>>>(
      pmaxk + PO2, pmink + PO2, psumg + PO2, sums2, gamma2, beta2, gptr, zbuf, 256, 384);
  wt_build_kernel<<<384, 256, 0, stream>>>(w_rel3, w_root3, b_rel3, sums2, gamma2, beta2,
                                           wt3, u3, v3, 256, 384);

  // ---- layer 3: 256 -> 384 ----
  agg_bf16_kernel<256><<<aggBlocks, 256, 0, stream>>>(hp2, rowptr, epack, aggb, nullptr);
  gemm_mfma_kernel<<<392 * 3, 256, 0, stream>>>(aggb, hp2, wt3, u3, v3, degw,
                                                hp3, sums3, N_NODES, 256, 384);
  pool_bf16_kernel<<<RB, 192, 0, stream>>>(hp3, batch, pmaxk + PO3, pmink + PO3, psumg + PO3,
                                           N_NODES, 384);
  pool_finalize_kernel<<<(N_GRAPH * 384 + 255) / 256, 256, 0, stream>>>(
      pmaxk + PO3, pmink + PO3, psumg + PO3, sums3, gamma3, beta3, gptr, zbuf, 384, 1152);

  // ---- FC head ----
  fc_kernel<<<N_GRAPH, 1024, 0, stream>>>(zbuf, w_lin1, b_lin1, w_lin2, b_lin2, w_lin3, b_lin3,
                                          outp);
}

// Round 14
// 577.043 us; speedup vs baseline: 1.0342x; 1.0089x over previous
//
#include <hip/hip_runtime.h>
#include <cstdint>
#include <cstddef>

#define N_NODES 50000
#define M_PAD   50048   // 391 * 128
#define MB_TILES 391
#define N_EDGES 800000
#define N_GRAPH 256
#define Z_DIM   2304
#define NREP    16
#define POOL_TOT (N_GRAPH * (128 + 256 + 384))

static constexpr float LEAKY  = 0.01f;
static constexpr float BN_EPS = 1e-5f;

typedef short short8 __attribute__((ext_vector_type(8)));
typedef float floatx4 __attribute__((ext_vector_type(4)));
typedef const __attribute__((address_space(1))) unsigned int* gas_ptr;
typedef __attribute__((address_space(3))) unsigned int* las_ptr;
typedef unsigned long long ull;

__device__ __forceinline__ unsigned short f2b(float f) {
  union { float f; unsigned int u; } v; v.f = f;
  unsigned int u = v.u;
  unsigned int r = (u + 0x7FFFu + ((u >> 16) & 1u)) >> 16;
  return (unsigned short)r;
}
__device__ __forceinline__ float b2f(unsigned short h) {
  union { unsigned int u; float f; } v; v.u = ((unsigned int)h) << 16;
  return v.f;
}
__device__ __forceinline__ unsigned fkey(float x) {
  unsigned k = __float_as_uint(x);
  return k ^ ((k & 0x80000000u) ? 0xFFFFFFFFu : 0x80000000u);
}
__device__ __forceinline__ float kdec(unsigned k) {
  k ^= (k & 0x80000000u) ? 0x80000000u : 0xFFFFFFFFu;
  return __uint_as_float(k);
}

// ---------------- one-shot init ----------------

__global__ void init_all_kernel(int* __restrict__ cntR, int* __restrict__ gcnt,
                                float* __restrict__ sums_all,
                                unsigned* __restrict__ pmaxk, unsigned* __restrict__ pmink,
                                float* __restrict__ psumg) {
  const int i = blockIdx.x * blockDim.x + threadIdx.x;
  if (i < NREP * N_NODES) cntR[i] = 0;
  if (i < N_GRAPH) gcnt[i] = 0;
  if (i < 2 * (128 + 256 + 384)) sums_all[i] = 0.f;
  if (i < POOL_TOT) { pmaxk[i] = 0u; pmink[i] = 0xFFFFFFFFu; psumg[i] = 0.f; }
}

// ---------------- CSR build (replicated histogram/cursor) ----------------

__global__ void hist_rep_kernel(const int* __restrict__ idx, int* __restrict__ cntR, int n) {
  int i = blockIdx.x * blockDim.x + threadIdx.x;
  if (i < n) {
    const int rep = blockIdx.x & (NREP - 1);
    atomicAdd(&cntR[rep * N_NODES + idx[i]], 1);
  }
}

// scan phase 1 fused with replica combine: reads cntR, prefixes replicas in place,
// computes node degree inline, then block-scans 1024 degrees.
__global__ __launch_bounds__(256) void scan1_fused_kernel(int* __restrict__ cntR,
                                                          int* __restrict__ out,
                                                          int* __restrict__ part, int n) {
  __shared__ int sm[256];
  const int t = threadIdx.x;
  const int base = blockIdx.x * 1024 + t * 4;
  int v[4] = {0, 0, 0, 0};
#pragma unroll
  for (int j = 0; j < 4; ++j) {
    const int d = base + j;
    if (d < n) {
      int s = 0;
#pragma unroll
      for (int r = 0; r < NREP; ++r) {
        const int c = cntR[r * N_NODES + d];
        cntR[r * N_NODES + d] = s;
        s += c;
      }
      v[j] = s;
    }
  }
  const int tsum = v[0] + v[1] + v[2] + v[3];
  sm[t] = tsum;
  __syncthreads();
  for (int off = 1; off < 256; off <<= 1) {
    int x = (t >= off) ? sm[t - off] : 0;
    __syncthreads();
    sm[t] += x;
    __syncthreads();
  }
  const int excl = sm[t] - tsum;
  if (base     < n) out[base]     = excl;
  if (base + 1 < n) out[base + 1] = excl + v[0];
  if (base + 2 < n) out[base + 2] = excl + v[0] + v[1];
  if (base + 3 < n) out[base + 3] = excl + v[0] + v[1] + v[2];
  if (t == 255) part[blockIdx.x] = sm[255];
}

__global__ __launch_bounds__(256) void scan2_kernel(int* __restrict__ part, int nb,
                                                    int* __restrict__ total_out) {
  __shared__ int sm[256];
  const int t = threadIdx.x;
  const int v = (t < nb) ? part[t] : 0;
  sm[t] = v;
  __syncthreads();
  for (int off = 1; off < 256; off <<= 1) {
    int x = (t >= off) ? sm[t - off] : 0;
    __syncthreads();
    sm[t] += x;
    __syncthreads();
  }
  if (t < nb) part[t] = sm[t] - v;
  if (t == 255) *total_out = sm[255];
}

__global__ void scan3_cursor_kernel(int* __restrict__ out, const int* __restrict__ part,
                                    int* __restrict__ cntR, int n) {
  int i = blockIdx.x * blockDim.x + threadIdx.x;
  if (i >= n) return;
  const int rp = out[i] + part[i >> 10];
  out[i] = rp;
#pragma unroll
  for (int r = 0; r < NREP; ++r) cntR[r * N_NODES + i] += rp;
}

__global__ void bucket_kernel(const int* __restrict__ src, const int* __restrict__ dst,
                              const float* __restrict__ ew, int* __restrict__ cntR,
                              ull* __restrict__ epack, int E) {
  int e = blockIdx.x * blockDim.x + threadIdx.x;
  if (e < E) {
    const int rep = blockIdx.x & (NREP - 1);
    const int d = dst[e];
    const int p = atomicAdd(&cntR[rep * N_NODES + d], 1);
    epack[p] = ((ull)__float_as_uint(ew[e]) << 32) | (unsigned)src[e];
  }
}

__global__ __launch_bounds__(256) void hist_batch_kernel(const int* __restrict__ idx,
                                                         int* __restrict__ cnt, int n) {
  __shared__ int lh[N_GRAPH];
  lh[threadIdx.x] = 0;
  __syncthreads();
  int i = blockIdx.x * blockDim.x + threadIdx.x;
  if (i < n) atomicAdd(&lh[idx[i]], 1);
  __syncthreads();
  const int v = lh[threadIdx.x];
  if (v) atomicAdd(&cnt[threadIdx.x], v);
}

__global__ __launch_bounds__(256) void scan256_kernel(const int* __restrict__ cnt,
                                                      int* __restrict__ gptr) {
  __shared__ int sm[256];
  const int t = threadIdx.x;
  const int v = cnt[t];
  sm[t] = v;
  __syncthreads();
  for (int off = 1; off < 256; off <<= 1) {
    int x = (t >= off) ? sm[t - off] : 0;
    __syncthreads();
    sm[t] += x;
    __syncthreads();
  }
  gptr[t] = sm[t] - v;
  if (t == 255) gptr[256] = sm[255];
}

// ---------------- prep ----------------

__global__ void cast_bf16_kernel(const float* __restrict__ in,
                                 unsigned short* __restrict__ out, int npair) {
  int i = blockIdx.x * blockDim.x + threadIdx.x;
  if (i >= npair) return;
  float2 v = *(const float2*)(in + 2 * (size_t)i);
  ((unsigned int*)out)[i] = (unsigned int)f2b(v.x) | ((unsigned int)f2b(v.y) << 16);
}

__global__ __launch_bounds__(256) void wt_build_kernel(
    const float* __restrict__ wrel, const float* __restrict__ wroot,
    const float* __restrict__ brel, const float* __restrict__ sums_prev,
    const float* __restrict__ gamma_prev, const float* __restrict__ beta_prev,
    unsigned short* __restrict__ wt, float* __restrict__ u, float* __restrict__ v,
    int K, int N) {
  __shared__ float redu[256];
  __shared__ float redv[256];
  const int n = blockIdx.x;
  const int K2 = 2 * K;
  const float inv_n = 1.f / (float)N_NODES;
  float us = 0.f, vs = 0.f;
  for (int k = threadIdx.x; k < K2; k += 256) {
    const int kk = (k < K) ? k : k - K;
    const float w = (k < K) ? wrel[(size_t)kk * N + n] : wroot[(size_t)kk * N + n];
    float sc = 1.f, sh = 0.f;
    if (sums_prev) {
      const float mu  = sums_prev[kk] * inv_n;
      const float var = sums_prev[K + kk] * inv_n - mu * mu;
      sc = rsqrtf(var + BN_EPS) * gamma_prev[kk];
      sh = beta_prev[kk] - mu * sc;
    }
    wt[(size_t)n * K2 + k] = f2b(w * sc);
    if (k < K) us += sh * w; else vs += sh * w;
  }
  redu[threadIdx.x] = us; redv[threadIdx.x] = vs;
  __syncthreads();
  for (int o = 128; o > 0; o >>= 1) {
    if (threadIdx.x < o) {
      redu[threadIdx.x] += redu[threadIdx.x + o];
      redv[threadIdx.x] += redv[threadIdx.x + o];
    }
    __syncthreads();
  }
  if (threadIdx.x == 0) { u[n] = redu[0]; v[n] = brel[n] + redv[0]; }
}

// ---------------- aggregation, 4-edge unrolled; optionally emits degw ----------------

template <int D>
__global__ void agg_bf16_kernel(const unsigned short* __restrict__ h,
                                const int* __restrict__ rowptr,
                                const ull* __restrict__ epack,
                                unsigned short* __restrict__ agg,
                                float* __restrict__ degw_out) {
  int gid  = blockIdx.x * blockDim.x + threadIdx.x;
  int node = gid >> 6;
  int lane = threadIdx.x & 63;
  if (node >= N_NODES) return;
  const int beg = rowptr[node], end = rowptr[node + 1];
  constexpr int NP = D / 128;
  float acc0[NP], acc1[NP];
#pragma unroll
  for (int i = 0; i < NP; ++i) { acc0[i] = 0.f; acc1[i] = 0.f; }
  float wsum = 0.f;

  int p = beg;
  for (; p + 4 <= end; p += 4) {
    const ull p0 = epack[p],     p1 = epack[p + 1];
    const ull p2 = epack[p + 2], p3 = epack[p + 3];
    const int s0 = (int)(unsigned)p0, s1 = (int)(unsigned)p1;
    const int s2 = (int)(unsigned)p2, s3 = (int)(unsigned)p3;
    const float w0 = __uint_as_float((unsigned)(p0 >> 32));
    const float w1 = __uint_as_float((unsigned)(p1 >> 32));
    const float w2 = __uint_as_float((unsigned)(p2 >> 32));
    const float w3 = __uint_as_float((unsigned)(p3 >> 32));
    wsum += w0 + w1 + w2 + w3;
    const unsigned int* r0 = (const unsigned int*)(h + (size_t)s0 * D);
    const unsigned int* r1 = (const unsigned int*)(h + (size_t)s1 * D);
    const unsigned int* r2 = (const unsigned int*)(h + (size_t)s2 * D);
    const unsigned int* r3 = (const unsigned int*)(h + (size_t)s3 * D);
    unsigned int u0[NP], u1[NP], u2[NP], u3[NP];
#pragma unroll
    for (int i = 0; i < NP; ++i) {
      u0[i] = r0[lane + 64 * i];
      u1[i] = r1[lane + 64 * i];
      u2[i] = r2[lane + 64 * i];
      u3[i] = r3[lane + 64 * i];
    }
#pragma unroll
    for (int i = 0; i < NP; ++i) {
      acc0[i] += b2f((unsigned short)(u0[i] & 0xFFFF)) * w0
               + b2f((unsigned short)(u1[i] & 0xFFFF)) * w1
               + b2f((unsigned short)(u2[i] & 0xFFFF)) * w2
               + b2f((unsigned short)(u3[i] & 0xFFFF)) * w3;
      acc1[i] += b2f((unsigned short)(u0[i] >> 16)) * w0
               + b2f((unsigned short)(u1[i] >> 16)) * w1
               + b2f((unsigned short)(u2[i] >> 16)) * w2
               + b2f((unsigned short)(u3[i] >> 16)) * w3;
    }
  }
  for (; p < end; ++p) {
    const ull pk = epack[p];
    const int   s = (int)(unsigned)pk;
    const float w = __uint_as_float((unsigned)(pk >> 32));
    wsum += w;
    const unsigned int* row = (const unsigned int*)(h + (size_t)s * D);
#pragma unroll
    for (int i = 0; i < NP; ++i) {
      unsigned int uu = row[lane + 64 * i];
      acc0[i] += b2f((unsigned short)(uu & 0xFFFF)) * w;
      acc1[i] += b2f((unsigned short)(uu >> 16)) * w;
    }
  }
  unsigned int* o = (unsigned int*)(agg + (size_t)node * D);
#pragma unroll
  for (int i = 0; i < NP; ++i)
    o[lane + 64 * i] = (unsigned int)f2b(acc0[i]) | ((unsigned int)f2b(acc1[i]) << 16);
  if (degw_out != nullptr && lane == 0) degw_out[node] = wsum;
}

// ---------------- MFMA GEMM: global_load_lds + XCD-affine tiles, BK=32 (round-12 shape) ----

__global__ __launch_bounds__(256) void gemm_mfma_kernel(
    const unsigned short* __restrict__ Aagg, const unsigned short* __restrict__ Ah,
    const unsigned short* __restrict__ Wt,
    const float* __restrict__ u, const float* __restrict__ v,
    const float* __restrict__ degw,
    unsigned short* __restrict__ outH, float* __restrict__ sums,
    int M, int K, int N) {
  __shared__ unsigned short As[128 * 32];
  __shared__ unsigned short Bs[128 * 32];
  __shared__ float col_s[256];
  __shared__ float dws[128];

  const int NT = N >> 7;
  const int id = blockIdx.x;
  const int xcd = id & 7;
  const int q   = id >> 3;
  const int m_tile = (q / NT) * 8 + xcd;
  if (m_tile >= MB_TILES) return;
  const int m0 = m_tile * 128;
  const int n0 = (q % NT) * 128;

  const int t  = threadIdx.x;
  const int lane = t & 63;
  const int w    = t >> 6;
  const int wm   = (w & 1) * 64;
  const int wn   = (w >> 1) * 64;
  const int l16  = lane & 15;
  const int lq   = lane >> 4;
  const int K2   = 2 * K;

  const int lrow  = lane >> 2;
  const int lslot = lane & 3;

  col_s[t] = 0.f;
  if (t < 128) {
    const int m = m0 + t;
    dws[t] = (m < M) ? degw[m] : 0.f;
  }

  floatx4 acc[4][4];
#pragma unroll
  for (int i = 0; i < 4; ++i)
#pragma unroll
    for (int j = 0; j < 4; ++j) acc[i][j] = (floatx4){0.f, 0.f, 0.f, 0.f};

  for (int k0 = 0; k0 < K2; k0 += 32) {
    const unsigned short* Asrc;
    int kbase;
    if (k0 < K) { Asrc = Aagg; kbase = k0; } else { Asrc = Ah; kbase = k0 - K; }

    __syncthreads();
#pragma unroll
    for (int qq = 0; qq < 2; ++qq) {
      const int row = w * 32 + qq * 16 + lrow;
      const int gc  = (lslot ^ ((row >> 1) & 3)) * 8;
      const unsigned short* gA = Asrc + (size_t)(m0 + row) * K + kbase + gc;
      const unsigned short* gB = Wt + (size_t)(n0 + row) * K2 + k0 + gc;
      __builtin_amdgcn_global_load_lds((gas_ptr)gA, (las_ptr)(As + (w * 32 + qq * 16) * 32),
                                       16, 0, 0);
      __builtin_amdgcn_global_load_lds((gas_ptr)gB, (las_ptr)(Bs + (w * 32 + qq * 16) * 32),
                                       16, 0, 0);
    }
    __syncthreads();

    short8 af[4], bfr[4];
#pragma unroll
    for (int i = 0; i < 4; ++i) {
      const int r = wm + i * 16 + l16;
      af[i] = *(const short8*)(As + r * 32 + (lq ^ ((r >> 1) & 3)) * 8);
    }
#pragma unroll
    for (int j = 0; j < 4; ++j) {
      const int r = wn + j * 16 + l16;
      bfr[j] = *(const short8*)(Bs + r * 32 + (lq ^ ((r >> 1) & 3)) * 8);
    }

#pragma unroll
    for (int i = 0; i < 4; ++i)
#pragma unroll
      for (int j = 0; j < 4; ++j)
        acc[i][j] = __builtin_amdgcn_mfma_f32_16x16x32_bf16(af[i], bfr[j], acc[i][j], 0, 0, 0);
  }

  float uu[4], vv[4];
#pragma unroll
  for (int j = 0; j < 4; ++j) {
    const int n = n0 + wn + j * 16 + l16;
    uu[j] = u[n]; vv[j] = v[n];
  }

  float ts[4]  = {0.f, 0.f, 0.f, 0.f};
  float tss[4] = {0.f, 0.f, 0.f, 0.f};
#pragma unroll
  for (int i = 0; i < 4; ++i) {
    const int lrow2 = wm + i * 16 + lq * 4;
#pragma unroll
    for (int j = 0; j < 4; ++j) {
      const int n = n0 + wn + j * 16 + l16;
#pragma unroll
      for (int r = 0; r < 4; ++r) {
        const int m = m0 + lrow2 + r;
        if (m < M) {
          float val = acc[i][j][r] + vv[j] + dws[lrow2 + r] * uu[j];
          val = val > 0.f ? val : LEAKY * val;
          outH[(size_t)m * N + n] = f2b(val);
          ts[j]  += val;
          tss[j] += val * val;
        }
      }
    }
  }
#pragma unroll
  for (int j = 0; j < 4; ++j) {
    float a = ts[j], b = tss[j];
    a += __shfl_xor(a, 16); a += __shfl_xor(a, 32);
    b += __shfl_xor(b, 16); b += __shfl_xor(b, 32);
    if (lq == 0) {
      const int ci = wn + j * 16 + l16;
      atomicAdd(&col_s[ci], a);
      atomicAdd(&col_s[128 + ci], b);
    }
  }
  __syncthreads();
  if (t < 128) {
    atomicAdd(&sums[n0 + t], col_s[t]);
    atomicAdd(&sums[N + n0 + t], col_s[128 + t]);
  }
}

// ---------------- pooling over bf16 hp ----------------

__global__ void pool_bf16_kernel(const unsigned short* __restrict__ hp,
                                 const int* __restrict__ batch,
                                 unsigned* __restrict__ pmaxk, unsigned* __restrict__ pmink,
                                 float* __restrict__ psumg, int n, int C) {
  __shared__ int bs[64];
  const int tc = threadIdx.x;
  const int r0 = blockIdx.x * 64;
  const int r1 = min(n, r0 + 64);
  if (tc < 64 && r0 + tc < n) bs[tc] = batch[r0 + tc];
  __syncthreads();
  int cur_g = bs[0];
  float mx0 = -3.4e38f, mn0 = 3.4e38f, s0 = 0.f;
  float mx1 = -3.4e38f, mn1 = 3.4e38f, s1 = 0.f;
  for (int r = r0; r < r1; ++r) {
    const int g = bs[r - r0];
    if (g != cur_g) {
      const int c0 = 2 * tc;
      atomicMax(&pmaxk[(size_t)cur_g * C + c0], fkey(mx0));
      atomicMin(&pmink[(size_t)cur_g * C + c0], fkey(mn0));
      atomicAdd(&psumg[(size_t)cur_g * C + c0], s0);
      atomicMax(&pmaxk[(size_t)cur_g * C + c0 + 1], fkey(mx1));
      atomicMin(&pmink[(size_t)cur_g * C + c0 + 1], fkey(mn1));
      atomicAdd(&psumg[(size_t)cur_g * C + c0 + 1], s1);
      mx0 = -3.4e38f; mn0 = 3.4e38f; s0 = 0.f;
      mx1 = -3.4e38f; mn1 = 3.4e38f; s1 = 0.f;
      cur_g = g;
    }
    const unsigned uu = ((const unsigned*)(hp + (size_t)r * C))[tc];
    const float a = b2f((unsigned short)(uu & 0xFFFF));
    const float b = b2f((unsigned short)(uu >> 16));
    mx0 = fmaxf(mx0, a); mn0 = fminf(mn0, a); s0 += a;
    mx1 = fmaxf(mx1, b); mn1 = fminf(mn1, b); s1 += b;
  }
  const int c0 = 2 * tc;
  atomicMax(&pmaxk[(size_t)cur_g * C + c0], fkey(mx0));
  atomicMin(&pmink[(size_t)cur_g * C + c0], fkey(mn0));
  atomicAdd(&psumg[(size_t)cur_g * C + c0], s0);
  atomicMax(&pmaxk[(size_t)cur_g * C + c0 + 1], fkey(mx1));
  atomicMin(&pmink[(size_t)cur_g * C + c0 + 1], fkey(mn1));
  atomicAdd(&psumg[(size_t)cur_g * C + c0 + 1], s1);
}

// ---------------- combined pool finalize: all 3 layers in one dispatch ----------------

__global__ void pool_finalize_all_kernel(const unsigned* __restrict__ pmaxk,
                                         const unsigned* __restrict__ pmink,
                                         const float* __restrict__ psumg,
                                         const float* __restrict__ sums_all,
                                         const float* __restrict__ gamma1, const float* __restrict__ beta1,
                                         const float* __restrict__ gamma2, const float* __restrict__ beta2,
                                         const float* __restrict__ gamma3, const float* __restrict__ beta3,
                                         const int* __restrict__ gptr,
                                         float* __restrict__ z) {
  int i = blockIdx.x * blockDim.x + threadIdx.x;
  if (i >= POOL_TOT) return;
  int C, zoff, li;
  const float *sums, *gamma, *beta;
  if (i < N_GRAPH * 128) {
    C = 128; zoff = 0; li = i;
    sums = sums_all; gamma = gamma1; beta = beta1;
  } else if (i < N_GRAPH * (128 + 256)) {
    C = 256; zoff = 384; li = i - N_GRAPH * 128;
    sums = sums_all + 2 * 128; gamma = gamma2; beta = beta2;
  } else {
    C = 384; zoff = 1152; li = i - N_GRAPH * (128 + 256);
    sums = sums_all + 2 * (128 + 256); gamma = gamma3; beta = beta3;
  }
  const int g = li / C, c = li % C;
  const int cnt = gptr[g + 1] - gptr[g];
  const float inv_n = 1.f / (float)N_NODES;
  const float mu  = sums[c] * inv_n;
  const float var = sums[C + c] * inv_n - mu * mu;
  const float sc  = rsqrtf(var + BN_EPS) * gamma[c];
  const float sh  = beta[c] - mu * sc;
  const float mx = kdec(pmaxk[i]);
  const float mn = kdec(pmink[i]);
  const float sm = psumg[i];
  const float zmax = (sc >= 0.f ? mx : mn) * sc + sh;
  const float zsum = sm * sc + (float)cnt * sh;
  float* zg = z + (size_t)g * Z_DIM + zoff;
  zg[c]         = (cnt > 0) ? zmax : 0.f;
  zg[C + c]     = zsum / (float)(cnt > 0 ? cnt : 1);
  zg[2 * C + c] = zsum;
}

// ---------------- FC head ----------------

__global__ __launch_bounds__(1024) void fc_kernel(const float* __restrict__ z,
                                                  const float* __restrict__ w1, const float* __restrict__ b1,
                                                  const float* __restrict__ w2, const float* __restrict__ b2,
                                                  const float* __restrict__ w3, const float* __restrict__ b3,
                                                  float* __restrict__ out) {
  __shared__ float zs[Z_DIM];
  __shared__ float part[8][128];
  __shared__ float h1s[128];
  __shared__ float red[128][2];
  __shared__ float y2[2];
  const int g  = blockIdx.x;
  const int t  = threadIdx.x;
  const int c  = t & 127;
  const int ks = t >> 7;
  for (int i = t; i < Z_DIM; i += 1024) zs[i] = z[(size_t)g * Z_DIM + i];
  __syncthreads();

  constexpr int KCH = Z_DIM / 8;
  const int k0 = ks * KCH;
  float acc = 0.f;
#pragma unroll 4
  for (int k = k0; k < k0 + KCH; ++k) acc += zs[k] * w1[(size_t)k * 128 + c];
  part[ks][c] = acc;
  __syncthreads();

  if (t < 128) {
    float s = b1[t];
#pragma unroll
    for (int i = 0; i < 8; ++i) s += part[i][t];
    h1s[t] = fmaxf(s, 0.f);
  }
  __syncthreads();
  if (t < 128) {
    red[t][0] = h1s[t] * w2[t * 2 + 0];
    red[t][1] = h1s[t] * w2[t * 2 + 1];
  }
  __syncthreads();
  if (t < 2) {
    float s = b2[t];
    for (int k = 0; k < 128; ++k) s += red[k][t];
    y2[t] = fmaxf(s, 0.f);
  }
  __syncthreads();
  if (t == 0) {
    const float z0 = y2[0] * w3[0] + y2[1] * w3[2] + b3[0];
    const float z1 = y2[0] * w3[1] + y2[1] * w3[3] + b3[1];
    const float m  = fmaxf(z0, z1);
    const float lse = m + logf(expf(z0 - m) + expf(z1 - m));
    out[g * 2 + 0] = z0 - lse;
    out[g * 2 + 1] = z1 - lse;
  }
}

// ---------------- launch ----------------

extern "C" void kernel_launch(void* const* d_in, const int* in_sizes, int n_in,
                              void* d_out, int out_size, void* d_ws, size_t ws_size,
                              hipStream_t stream) {
  (void)in_sizes; (void)n_in; (void)out_size; (void)ws_size;
  const float* x        = (const float*)d_in[0];
  const int*   eidx     = (const int*)d_in[1];
  const int*   batch    = (const int*)d_in[2];
  const float* eattr    = (const float*)d_in[3];
  const float* w_rel1   = (const float*)d_in[4];
  const float* b_rel1   = (const float*)d_in[5];
  const float* w_root1  = (const float*)d_in[6];
  const float* w_rel2   = (const float*)d_in[7];
  const float* b_rel2   = (const float*)d_in[8];
  const float* w_root2  = (const float*)d_in[9];
  const float* w_rel3   = (const float*)d_in[10];
  const float* b_rel3   = (const float*)d_in[11];
  const float* w_root3  = (const float*)d_in[12];
  const float* gamma1   = (const float*)d_in[13];
  const float* beta1    = (const float*)d_in[14];
  const float* gamma2   = (const float*)d_in[15];
  const float* beta2    = (const float*)d_in[16];
  const float* gamma3   = (const float*)d_in[17];
  const float* beta3    = (const float*)d_in[18];
  const float* w_lin1   = (const float*)d_in[19];
  const float* b_lin1   = (const float*)d_in[20];
  const float* w_lin2   = (const float*)d_in[21];
  const float* b_lin2   = (const float*)d_in[22];
  const float* w_lin3   = (const float*)d_in[23];
  const float* b_lin3   = (const float*)d_in[24];

  const int* src = eidx;
  const int* dst = eidx + N_EDGES;
  float* outp = (float*)d_out;

  char* ws = (char*)d_ws;
  size_t off = 0;
  auto alloc = [&](size_t bytes) -> void* {
    void* p = ws + off;
    off += (bytes + 255) & ~(size_t)255;
    return p;
  };
  int*   rowptr = (int*)alloc((N_NODES + 1) * sizeof(int));
  int*   cntR   = (int*)alloc((size_t)NREP * N_NODES * sizeof(int));
  int*   gptr   = (int*)alloc((N_GRAPH + 1) * sizeof(int));
  int*   gcnt   = (int*)alloc(N_GRAPH * sizeof(int));
  int*   part   = (int*)alloc(256 * sizeof(int));
  ull*   epack  = (ull*)alloc((size_t)N_EDGES * sizeof(ull));
  float* degw   = (float*)alloc(N_NODES * sizeof(float));
  float* sums_all = (float*)alloc(2 * (128 + 256 + 384) * sizeof(float));
  float* zbuf   = (float*)alloc((size_t)N_GRAPH * Z_DIM * sizeof(float));
  unsigned* pmaxk = (unsigned*)alloc((size_t)POOL_TOT * 4);
  unsigned* pmink = (unsigned*)alloc((size_t)POOL_TOT * 4);
  float*    psumg = (float*)alloc((size_t)POOL_TOT * 4);
  unsigned short* xb   = (unsigned short*)alloc((size_t)M_PAD * 128 * 2);
  unsigned short* hp1  = (unsigned short*)alloc((size_t)M_PAD * 128 * 2);
  unsigned short* hp2  = (unsigned short*)alloc((size_t)M_PAD * 256 * 2);
  unsigned short* hp3  = (unsigned short*)alloc((size_t)M_PAD * 384 * 2);
  unsigned short* aggb = (unsigned short*)alloc((size_t)M_PAD * 256 * 2);
  unsigned short* wt1 = (unsigned short*)alloc((size_t)128 * 256 * 2);
  unsigned short* wt2 = (unsigned short*)alloc((size_t)256 * 256 * 2);
  unsigned short* wt3 = (unsigned short*)alloc((size_t)384 * 512 * 2);
  float* u1 = (float*)alloc(128 * sizeof(float));
  float* v1 = (float*)alloc(128 * sizeof(float));
  float* u2 = (float*)alloc(256 * sizeof(float));
  float* v2 = (float*)alloc(256 * sizeof(float));
  float* u3 = (float*)alloc(384 * sizeof(float));
  float* v3 = (float*)alloc(384 * sizeof(float));

  float* sums1 = sums_all;
  float* sums2 = sums_all + 2 * 128;
  float* sums3 = sums_all + 2 * (128 + 256);
  const int PO1 = 0, PO2 = N_GRAPH * 128, PO3 = N_GRAPH * (128 + 256);

  const int EB = (N_EDGES + 255) / 256;
  const int NB = (N_NODES + 255) / 256;
  const int RB = (N_NODES + 63) / 64;
  const int SB = (N_NODES + 1023) / 1024;

  init_all_kernel<<<(NREP * N_NODES + 255) / 256, 256, 0, stream>>>(
      cntR, gcnt, sums_all, pmaxk, pmink, psumg);

  // ---- CSR by dst ----
  hist_rep_kernel<<<EB, 256, 0, stream>>>(dst, cntR, N_EDGES);
  scan1_fused_kernel<<<SB, 256, 0, stream>>>(cntR, rowptr, part, N_NODES);
  scan2_kernel<<<1, 256, 0, stream>>>(part, SB, rowptr + N_NODES);
  scan3_cursor_kernel<<<NB, 256, 0, stream>>>(rowptr, part, cntR, N_NODES);
  bucket_kernel<<<EB, 256, 0, stream>>>(src, dst, eattr, cntR, epack, N_EDGES);

  // ---- graph segment pointers ----
  hist_batch_kernel<<<NB, 256, 0, stream>>>(batch, gcnt, N_NODES);
  scan256_kernel<<<1, 256, 0, stream>>>(gcnt, gptr);

  // ---- prep ----
  cast_bf16_kernel<<<(N_NODES * 128 / 2 + 255) / 256, 256, 0, stream>>>(x, xb, N_NODES * 128 / 2);
  wt_build_kernel<<<128, 256, 0, stream>>>(w_rel1, w_root1, b_rel1, nullptr, nullptr, nullptr,
                                           wt1, u1, v1, 128, 128);

  const int aggBlocks = (N_NODES * 64 + 255) / 256;

  // ---- layer 1: 128 -> 128 ----
  agg_bf16_kernel<128><<<aggBlocks, 256, 0, stream>>>(xb, rowptr, epack, aggb, degw);
  gemm_mfma_kernel<<<392 * 1, 256, 0, stream>>>(aggb, xb, wt1, u1, v1, degw,
                                                hp1, sums1, N_NODES, 128, 128);
  pool_bf16_kernel<<<RB, 64, 0, stream>>>(hp1, batch, pmaxk + PO1, pmink + PO1, psumg + PO1,
                                          N_NODES, 128);
  wt_build_kernel<<<256, 256, 0, stream>>>(w_rel2, w_root2, b_rel2, sums1, gamma1, beta1,
                                           wt2, u2, v2, 128, 256);

  // ---- layer 2: 128 -> 256 ----
  agg_bf16_kernel<128><<<aggBlocks, 256, 0, stream>>>(hp1, rowptr, epack, aggb, nullptr);
  gemm_mfma_kernel<<<392 * 2, 256, 0, stream>>>(aggb, hp1, wt2, u2, v2, degw,
                                                hp2, sums2, N_NODES, 128, 256);
  pool_bf16_kernel<<<RB, 128, 0, stream>>>(hp2, batch, pmaxk + PO2, pmink + PO2, psumg + PO2,
                                           N_NODES, 256);
  wt_build_kernel<<<384, 256, 0, stream>>>(w_rel3, w_root3, b_rel3, sums2, gamma2, beta2,
                                           wt3, u3, v3, 256, 384);

  // ---- layer 3: 256 -> 384 ----
  agg_bf16_kernel<256><<<aggBlocks, 256, 0, stream>>>(hp2, rowptr, epack, aggb, nullptr);
  gemm_mfma_kernel<<<392 * 3, 256, 0, stream>>>(aggb, hp2, wt3, u3, v3, degw,
                                                hp3, sums3, N_NODES, 256, 384);
  pool_bf16_kernel<<<RB, 192, 0, stream>>>(hp3, batch, pmaxk + PO3, pmink + PO3, psumg + PO3,
                                           N_NODES, 384);

  // ---- combined pool finalize (all layers) + FC head ----
  pool_finalize_all_kernel<<<(POOL_TOT + 255) / 256, 256, 0, stream>>>(
      pmaxk, pmink, psumg, sums_all, gamma1, beta1, gamma2, beta2, gamma3, beta3, gptr, zbuf);
  fc_kernel<<<N_GRAPH, 1024, 0, stream>>>(zbuf, w_lin1, b_lin1, w_lin2, b_lin2, w_lin3, b_lin3,
                                          outp);
}